// Round 6
// baseline (492.780 us; speedup 1.0000x reference)
//
#include <hip/hip_runtime.h>

#define N_NODES 100000
#define IN_CH 128
#define HID 75
#define OUT_CH 40
#define N_EDGES 3200000

#define NB 196          // buckets of 512 dst nodes
#define CAP 20000       // per-bucket capacity; mean 16384
#define EPT 16          // edges per thread in passA
#define PA_EDGES (EPT * 256)

#define BLK_NODES 49    // nodes per aggregation block (LDS-resident accum)
#define SLICE 12500     // src-slice width: 12500*192B = 2.4MB < 4MB L2/XCD

typedef unsigned short u16;
typedef unsigned int u32;
typedef unsigned long long u64;
typedef short short8 __attribute__((ext_vector_type(8)));
typedef float f32x4 __attribute__((ext_vector_type(4)));

__device__ __forceinline__ float bf2f(u16 u) {
    return __uint_as_float(((u32)u) << 16);
}
__device__ __forceinline__ u16 f2bf(float f) {
    u32 b = __float_as_uint(f);
    b += 0x7FFF + ((b >> 16) & 1);   // round-to-nearest-even
    return (u16)(b >> 16);
}

// ---------------- edge-index layout probe (int32 vs int64) ----------------
__global__ void probe64(const int* __restrict__ e, int* __restrict__ flag) {
    __shared__ int nonzero;
    if (threadIdx.x == 0) nonzero = 0;
    __syncthreads();
    int idx = threadIdx.x * 12497;              // < 3.2M
    if (e[2 * idx + 1] != 0) nonzero = 1;       // safe for both layouts
    __syncthreads();
    if (threadIdx.x == 0) *flag = (nonzero == 0) ? 1 : 0;
}

__global__ __launch_bounds__(256) void init_zero(int* __restrict__ bucketCursor) {
    int i = blockIdx.x * 256 + threadIdx.x;
    if (i < NB * 16) bucketCursor[i] = 0;
}

// ---------------- pass A: bin edges into 196 dst-range buckets ------------
__global__ __launch_bounds__(256) void passA(const int* __restrict__ e,
        const int* __restrict__ flag, int* __restrict__ bucketCursor,
        unsigned* __restrict__ bucketBuf) {
    __shared__ int cnt[NB];
    __shared__ int base[NB];
    int t = threadIdx.x;
    for (int i = t; i < NB; i += 256) cnt[i] = 0;
    __syncthreads();
    bool w64 = (*flag != 0);
    int s_[EPT], d_[EPT];
    int eb = blockIdx.x * PA_EDGES + t;
#pragma unroll
    for (int k = 0; k < EPT; ++k) {
        int idx = eb + k * 256;
        int s = 0, d = -1;
        if (idx < N_EDGES) {
            if (w64) { s = e[2 * idx]; d = e[2 * (N_EDGES + idx)]; }
            else     { s = e[idx];     d = e[N_EDGES + idx]; }
            atomicAdd(&cnt[d >> 9], 1);
        }
        s_[k] = s; d_[k] = d;
    }
    __syncthreads();
    for (int i = t; i < NB; i += 256) {
        int c = cnt[i];
        base[i] = (c > 0) ? atomicAdd(&bucketCursor[i * 16], c) : 0;  // 64B-padded cursors
        cnt[i] = 0;
    }
    __syncthreads();
#pragma unroll
    for (int k = 0; k < EPT; ++k) {
        int d = d_[k];
        if (d >= 0) {
            int b = d >> 9;
            int off = atomicAdd(&cnt[b], 1);
            int pos = base[b] + off;
            if (pos < CAP)
                bucketBuf[(size_t)b * CAP + pos] =
                    ((unsigned)(d & 511) << 17) | (unsigned)s_[k];
        }
    }
}

// ---------------- scan of 196 bucket sizes -> bucket starts ---------------
__global__ __launch_bounds__(256) void scan196(const int* __restrict__ bucketCursor,
        int* __restrict__ bucketStart, int* __restrict__ rowStart) {
    __shared__ int a[256], b[256];
    int t = threadIdx.x;
    int v = (t < NB) ? bucketCursor[t * 16] : 0;
    a[t] = v;
    __syncthreads();
    int* pin = a; int* pout = b;
    for (int o = 1; o < 256; o <<= 1) {
        int nv = pin[t] + ((t >= o) ? pin[t - o] : 0);
        pout[t] = nv;
        __syncthreads();
        int* tmp = pin; pin = pout; pout = tmp;
    }
    if (t < NB) bucketStart[t] = pin[t] - v;  // exclusive
    if (t == 0) rowStart[N_NODES] = N_EDGES;
}

// ---------------- pass B: per-bucket CSR fill, all atomics in LDS ---------
__global__ __launch_bounds__(1024) void passB(const unsigned* __restrict__ bucketBuf,
        const int* __restrict__ bucketCursor, const int* __restrict__ bucketStart,
        int* __restrict__ csrSrc, int* __restrict__ rowStart, float* __restrict__ dinv) {
    __shared__ int cnt[512];
    __shared__ int sa[512], sb[512];
    int b = blockIdx.x;
    int t = threadIdx.x;
    int n = bucketCursor[b * 16];
    int start = bucketStart[b];
    if (t < 512) cnt[t] = 0;
    __syncthreads();
    const unsigned* buf = bucketBuf + (size_t)b * CAP;
    for (int i = t; i < n; i += 1024) atomicAdd(&cnt[buf[i] >> 17], 1);
    __syncthreads();
    if (t < 512) sa[t] = cnt[t];
    __syncthreads();
    int* pin = sa; int* pout = sb;
    for (int o = 1; o < 512; o <<= 1) {
        if (t < 512) pout[t] = pin[t] + ((t >= o) ? pin[t - o] : 0);
        __syncthreads();
        int* tmp = pin; pin = pout; pout = tmp;
    }
    int excl = 0;
    if (t < 512) {
        int deg = cnt[t];
        excl = pin[t] - deg;
        int node = b * 512 + t;
        if (node < N_NODES) {
            rowStart[node] = start + excl;
            dinv[node] = rsqrtf((float)deg + 1.0f);  // +1 self-loop
        }
    }
    __syncthreads();
    if (t < 512) cnt[t] = excl;   // LDS cursors
    __syncthreads();
    for (int i = t; i < n; i += 1024) {
        unsigned p = buf[i];
        int pos = atomicAdd(&cnt[p >> 17], 1);
        csrSrc[start + pos] = (int)(p & 0x1FFFF);
    }
}

// ---------------- sort rows + emit per-slice phase boundaries -------------
// phaseOff[node] byte k (k=0..6) = #edges (of first min(deg,64)) with
// src < (k+1)*SLICE. Phase k edge range: [off[k-1], off[k]); phase 7 ends
// at deg (covers deg>64 tail unconditionally).
__global__ __launch_bounds__(256) void sort_rows(const int* __restrict__ rowStart,
        int* __restrict__ csrSrc, u64* __restrict__ phaseOff) {
    int wid = threadIdx.x >> 6;
    int lane = threadIdx.x & 63;
    int node = blockIdx.x * 4 + wid;
    if (node >= N_NODES) return;
    int j0 = rowStart[node];
    int n = rowStart[node + 1] - j0;
    int nn = min(n, 64);
    int v = (lane < nn) ? csrSrc[j0 + lane] : 0x7FFFFFFF;
    if (nn >= 2) {
#pragma unroll
        for (int k = 2; k <= 64; k <<= 1) {
#pragma unroll
            for (int j = k >> 1; j > 0; j >>= 1) {
                int ex = __shfl_xor(v, j);
                bool asc = ((lane & k) == 0);
                bool upper = ((lane & j) != 0);
                int mn = min(v, ex), mx = max(v, ex);
                v = (asc != upper) ? mn : mx;
            }
        }
        if (lane < nn) csrSrc[j0 + lane] = v;
    }
    u64 po = 0;
#pragma unroll
    for (int k = 0; k < 7; ++k) {
        u64 cnt = __popcll(__ballot((lane < nn) && (v < (k + 1) * SLICE)));
        po |= cnt << (8 * k);
    }
    if (lane == 0) phaseOff[node] = po;
}

// ---------------- prep: bf16 transposed weights ---------------------------
__global__ __launch_bounds__(256) void prep_w(const float* __restrict__ W1,
        const float* __restrict__ W2, u16* __restrict__ w1t, u16* __restrict__ w2t) {
    int g = blockIdx.x * 256 + threadIdx.x;
    int stride = gridDim.x * 256;
    for (int i = g; i < 80 * 128; i += stride) {
        int c = i >> 7, k = i & 127;
        w1t[i] = (c < HID) ? f2bf(W1[k * HID + c]) : (u16)0;
    }
    for (int i = g; i < 48 * 96; i += stride) {
        int c = i / 96, k = i - c * 96;
        w2t[i] = (c < OUT_CH && k < HID) ? f2bf(W2[k * OUT_CH + c]) : (u16)0;
    }
}

// ---------------- GEMM1 via MFMA: hs1 = bf16(dinv * (x @ W1)), stride 96 --
__global__ __launch_bounds__(256) void gemm1_mfma(const float* __restrict__ x,
        const u16* __restrict__ w1t, const float* __restrict__ dinv,
        u16* __restrict__ hs1) {
    __shared__ u16 Wl[80 * 136];   // pad 128->136 elems: bank-spread rows
    int t = threadIdx.x;
    {
        const u32* ws = (const u32*)w1t;
        u32* wd = (u32*)Wl;
        for (int i = t; i < 80 * 64; i += 256) {
            int r = i >> 6, c = i & 63;
            wd[r * 68 + c] = ws[i];
        }
    }
    __syncthreads();
    int wid = t >> 6, lane = t & 63;
    int bl = lane & 15, kh = lane >> 4;
    int row0 = blockIdx.x * 64 + wid * 16;
    short8 bf[5][4];
#pragma unroll
    for (int ct = 0; ct < 5; ++ct)
#pragma unroll
        for (int ks = 0; ks < 4; ++ks)
            bf[ct][ks] = *(const short8*)&Wl[(ct * 16 + bl) * 136 + ks * 32 + kh * 8];
    f32x4 zero = {0.f, 0.f, 0.f, 0.f};
    f32x4 acc[5];
#pragma unroll
    for (int ct = 0; ct < 5; ++ct) acc[ct] = zero;
    int arow = row0 + bl;
    bool av = (arow < N_NODES);
    const float* xr = x + (size_t)arow * IN_CH + kh * 8;
#pragma unroll
    for (int ks = 0; ks < 4; ++ks) {
        short8 af = {0, 0, 0, 0, 0, 0, 0, 0};
        if (av) {
            float4 lo = *(const float4*)(xr + ks * 32);
            float4 hi = *(const float4*)(xr + ks * 32 + 4);
            af[0] = (short)f2bf(lo.x); af[1] = (short)f2bf(lo.y);
            af[2] = (short)f2bf(lo.z); af[3] = (short)f2bf(lo.w);
            af[4] = (short)f2bf(hi.x); af[5] = (short)f2bf(hi.y);
            af[6] = (short)f2bf(hi.z); af[7] = (short)f2bf(hi.w);
        }
#pragma unroll
        for (int ct = 0; ct < 5; ++ct)
            acc[ct] = __builtin_amdgcn_mfma_f32_16x16x32_bf16(af, bf[ct][ks], acc[ct], 0, 0, 0);
    }
    // C/D: col = lane&15, row = (lane>>4)*4 + reg  [HW-verified]
    int orow = row0 + kh * 4;
    float dn[4];
#pragma unroll
    for (int i = 0; i < 4; ++i) dn[i] = (orow + i < N_NODES) ? dinv[orow + i] : 0.f;
#pragma unroll
    for (int ct = 0; ct < 5; ++ct) {
        int col = ct * 16 + bl;
#pragma unroll
        for (int i = 0; i < 4; ++i) {
            int r = orow + i;
            if (r < N_NODES) hs1[(size_t)r * 96 + col] = f2bf(acc[ct][i] * dn[i]);
        }
    }
}

// ---------------- GEMM2 via MFMA: hs2 = bf16(dinv * (h1 @ W2)), stride 48 -
__global__ __launch_bounds__(256) void gemm2_mfma(const u16* __restrict__ h1b,
        const u16* __restrict__ w2t, const float* __restrict__ dinv,
        u16* __restrict__ hs2) {
    __shared__ u16 Wl[48 * 104];   // pad 96->104
    int t = threadIdx.x;
    {
        const u32* ws = (const u32*)w2t;
        u32* wd = (u32*)Wl;
        for (int i = t; i < 48 * 48; i += 256) {
            int r = i / 48, c = i - r * 48;
            wd[r * 52 + c] = ws[i];
        }
    }
    __syncthreads();
    int wid = t >> 6, lane = t & 63;
    int bl = lane & 15, kh = lane >> 4;
    int row0 = blockIdx.x * 64 + wid * 16;
    short8 bf[3][3];
#pragma unroll
    for (int ct = 0; ct < 3; ++ct)
#pragma unroll
        for (int ks = 0; ks < 3; ++ks)
            bf[ct][ks] = *(const short8*)&Wl[(ct * 16 + bl) * 104 + ks * 32 + kh * 8];
    f32x4 zero = {0.f, 0.f, 0.f, 0.f};
    f32x4 acc[3];
#pragma unroll
    for (int ct = 0; ct < 3; ++ct) acc[ct] = zero;
    int arow = row0 + bl;
    bool av = (arow < N_NODES);
    const u16* hr = h1b + (size_t)arow * 96 + kh * 8;
#pragma unroll
    for (int ks = 0; ks < 3; ++ks) {
        short8 af = {0, 0, 0, 0, 0, 0, 0, 0};
        if (av) af = *(const short8*)(hr + ks * 32);
#pragma unroll
        for (int ct = 0; ct < 3; ++ct)
            acc[ct] = __builtin_amdgcn_mfma_f32_16x16x32_bf16(af, bf[ct][ks], acc[ct], 0, 0, 0);
    }
    int orow = row0 + kh * 4;
    float dn[4];
#pragma unroll
    for (int i = 0; i < 4; ++i) dn[i] = (orow + i < N_NODES) ? dinv[orow + i] : 0.f;
#pragma unroll
    for (int ct = 0; ct < 3; ++ct) {
        int col = ct * 16 + bl;
#pragma unroll
        for (int i = 0; i < 4; ++i) {
            int r = orow + i;
            if (r < N_NODES) hs2[(size_t)r * 48 + col] = f2bf(acc[ct][i] * dn[i]);
        }
    }
}

// ---------------- agg layer 1: phased block-resident LDS accumulation -----
// 8 src-slice phases of 2.4MB each; all 2041 blocks co-resident (8/CU),
// sweeping slices in lockstep -> per-XCD L2 working set ~= one slice.
__global__ __launch_bounds__(256, 8) void agg1_phase(
        const u32* __restrict__ tab, const int* __restrict__ rowStart,
        const int* __restrict__ csrSrc, const u64* __restrict__ phaseOff,
        const float* __restrict__ dinv, const float* __restrict__ bias,
        u32* __restrict__ out) {
    __shared__ float accLo[BLK_NODES][48];
    __shared__ float accHi[BLK_NODES][48];
    int t = threadIdx.x;
    int wid = t >> 6, lane = t & 63;
    int nb = blockIdx.x * BLK_NODES;
    bool act = lane < 48;
    for (int n = wid; n < BLK_NODES; n += 4) {          // init = self-loop row
        int node = nb + n;
        if (node < N_NODES && act) {
            u32 v = tab[(size_t)node * 48 + lane];
            accLo[n][lane] = __uint_as_float(v << 16);
            accHi[n][lane] = __uint_as_float(v & 0xFFFF0000u);
        }
    }
    __syncthreads();
    for (int ph = 0; ph < 8; ++ph) {
        for (int n = wid; n < BLK_NODES; n += 4) {
            int node = __builtin_amdgcn_readfirstlane(nb + n);
            if (node >= N_NODES) continue;
            int rs = rowStart[node];
            int deg = rowStart[node + 1] - rs;
            u64 po = phaseOff[node];
            int lo = ph ? (int)((po >> (8 * (ph - 1))) & 0xFFull) : 0;
            int hi = (ph < 7) ? (int)((po >> (8 * ph)) & 0xFFull) : deg;
            if (hi <= lo) continue;
            float aLo = 0.f, aHi = 0.f;
            int j = lo;
            for (; j + 4 <= hi; j += 4) {
                u32 v[4];
#pragma unroll
                for (int q = 0; q < 4; ++q) {
                    int idx = csrSrc[rs + j + q];       // uniform -> s_load
                    v[q] = act ? tab[(size_t)idx * 48 + lane] : 0u;
                }
#pragma unroll
                for (int q = 0; q < 4; ++q) {
                    aLo += __uint_as_float(v[q] << 16);
                    aHi += __uint_as_float(v[q] & 0xFFFF0000u);
                }
            }
            for (; j < hi; ++j) {
                int idx = csrSrc[rs + j];
                u32 v = act ? tab[(size_t)idx * 48 + lane] : 0u;
                aLo += __uint_as_float(v << 16);
                aHi += __uint_as_float(v & 0xFFFF0000u);
            }
            if (act) { accLo[n][lane] += aLo; accHi[n][lane] += aHi; }
        }
        __syncthreads();
    }
    for (int n = wid; n < BLK_NODES; n += 4) {          // epilogue
        int node = nb + n;
        if (node < N_NODES && act) {
            float dn = dinv[node];
            int c0 = 2 * lane, c1 = c0 + 1;
            float rlo = (c0 < HID) ? fmaxf(fmaf(dn, accLo[n][lane], bias[c0]), 0.f) : 0.f;
            float rhi = (c1 < HID) ? fmaxf(fmaf(dn, accHi[n][lane], bias[c1]), 0.f) : 0.f;
            out[(size_t)node * 48 + lane] = ((u32)f2bf(rhi) << 16) | (u32)f2bf(rlo);
        }
    }
}

// ---------------- agg layer 2: phased + fused log_softmax -----------------
__global__ __launch_bounds__(256, 8) void agg2_phase(
        const u32* __restrict__ tab, const int* __restrict__ rowStart,
        const int* __restrict__ csrSrc, const u64* __restrict__ phaseOff,
        const float* __restrict__ dinv, const float* __restrict__ bias,
        float* __restrict__ out) {
    __shared__ float accLo[BLK_NODES][24];
    __shared__ float accHi[BLK_NODES][24];
    int t = threadIdx.x;
    int wid = t >> 6, lane = t & 63;
    int nb = blockIdx.x * BLK_NODES;
    bool act = lane < 24;
    for (int n = wid; n < BLK_NODES; n += 4) {          // init = self-loop row
        int node = nb + n;
        if (node < N_NODES && act) {
            u32 v = tab[(size_t)node * 24 + lane];
            accLo[n][lane] = __uint_as_float(v << 16);
            accHi[n][lane] = __uint_as_float(v & 0xFFFF0000u);
        }
    }
    __syncthreads();
    for (int ph = 0; ph < 8; ++ph) {
        for (int n = wid; n < BLK_NODES; n += 4) {
            int node = __builtin_amdgcn_readfirstlane(nb + n);
            if (node >= N_NODES) continue;
            int rs = rowStart[node];
            int deg = rowStart[node + 1] - rs;
            u64 po = phaseOff[node];
            int lo = ph ? (int)((po >> (8 * (ph - 1))) & 0xFFull) : 0;
            int hi = (ph < 7) ? (int)((po >> (8 * ph)) & 0xFFull) : deg;
            if (hi <= lo) continue;
            float aLo = 0.f, aHi = 0.f;
            int j = lo;
            for (; j + 4 <= hi; j += 4) {
                u32 v[4];
#pragma unroll
                for (int q = 0; q < 4; ++q) {
                    int idx = csrSrc[rs + j + q];
                    v[q] = act ? tab[(size_t)idx * 24 + lane] : 0u;
                }
#pragma unroll
                for (int q = 0; q < 4; ++q) {
                    aLo += __uint_as_float(v[q] << 16);
                    aHi += __uint_as_float(v[q] & 0xFFFF0000u);
                }
            }
            for (; j < hi; ++j) {
                int idx = csrSrc[rs + j];
                u32 v = act ? tab[(size_t)idx * 24 + lane] : 0u;
                aLo += __uint_as_float(v << 16);
                aHi += __uint_as_float(v & 0xFFFF0000u);
            }
            if (act) { accLo[n][lane] += aLo; accHi[n][lane] += aHi; }
        }
        __syncthreads();
    }
    for (int n = wid; n < BLK_NODES; n += 4) {          // epilogue: log_softmax
        int node = nb + n;
        bool valid = node < N_NODES;
        bool act20 = valid && (lane < 20);
        float dn = valid ? dinv[node] : 0.f;
        float v0 = 0.f, v1 = 0.f, m = -3.4e38f;
        if (act20) {
            v0 = fmaf(dn, accLo[n][lane], bias[2 * lane]);
            v1 = fmaf(dn, accHi[n][lane], bias[2 * lane + 1]);
            m = fmaxf(v0, v1);
        }
#pragma unroll
        for (int o = 32; o > 0; o >>= 1) m = fmaxf(m, __shfl_xor(m, o));
        float e = act20 ? (expf(v0 - m) + expf(v1 - m)) : 0.f;
#pragma unroll
        for (int o = 32; o > 0; o >>= 1) e += __shfl_xor(e, o);
        float lse = logf(e);
        if (act20) {
            float2 r = make_float2(v0 - m - lse, v1 - m - lse);
            *reinterpret_cast<float2*>(out + (size_t)node * OUT_CH + 2 * lane) = r;
        }
    }
}

extern "C" void kernel_launch(void* const* d_in, const int* in_sizes, int n_in,
                              void* d_out, int out_size, void* d_ws, size_t ws_size,
                              hipStream_t stream) {
    const float* x  = (const float*)d_in[0];
    const int*   e  = (const int*)d_in[1];
    const float* W1 = (const float*)d_in[2];
    const float* b1 = (const float*)d_in[3];
    const float* W2 = (const float*)d_in[4];
    const float* b2 = (const float*)d_in[5];
    float* out = (float*)d_out;

    // workspace carve (all sizes multiples of 16 B); total ~63 MB
    char* w = (char*)d_ws;
    unsigned* bucketBuf = (unsigned*)w;              // 15.68 MB, dead after passB
    u16* hs1  = (u16*)w; w += (size_t)100032 * 96 * 2;   // 19.2 MB (aliases bucketBuf)
    u16* h1b  = (u16*)w; w += (size_t)100032 * 96 * 2;   // 19.2 MB
    int* csrSrc = (int*)w; w += (size_t)N_EDGES * 4;     // 12.8 MB
    u16* hs2  = (u16*)w; w += (size_t)100000 * 48 * 2;   // 9.6 MB
    int* rowStart = (int*)w; w += 400016;
    float* dinv   = (float*)w; w += 400000;
    u64* phaseOff = (u64*)w; w += 800000;
    int* bucketCursor = (int*)w; w += NB * 16 * 4;
    int* bucketStart  = (int*)w; w += 1024;
    u16* w1t = (u16*)w; w += 80 * 128 * 2;
    u16* w2t = (u16*)w; w += 48 * 96 * 2;
    int* flag = (int*)w; w += 16;

    probe64<<<1, 256, 0, stream>>>(e, flag);
    init_zero<<<(NB * 16 + 255) / 256, 256, 0, stream>>>(bucketCursor);
    passA<<<(N_EDGES + PA_EDGES - 1) / PA_EDGES, 256, 0, stream>>>(
        e, flag, bucketCursor, bucketBuf);
    scan196<<<1, 256, 0, stream>>>(bucketCursor, bucketStart, rowStart);
    passB<<<NB, 1024, 0, stream>>>(bucketBuf, bucketCursor, bucketStart,
                                   csrSrc, rowStart, dinv);
    sort_rows<<<(N_NODES + 3) / 4, 256, 0, stream>>>(rowStart, csrSrc, phaseOff);
    prep_w<<<16, 256, 0, stream>>>(W1, W2, w1t, w2t);

    int aggGrid = (N_NODES + BLK_NODES - 1) / BLK_NODES;   // 2041
    gemm1_mfma<<<(N_NODES + 63) / 64, 256, 0, stream>>>(x, w1t, dinv, hs1);
    agg1_phase<<<aggGrid, 256, 0, stream>>>(
        (const u32*)hs1, rowStart, csrSrc, phaseOff, dinv, b1, (u32*)h1b);
    gemm2_mfma<<<(N_NODES + 63) / 64, 256, 0, stream>>>(h1b, w2t, dinv, hs2);
    agg2_phase<<<aggGrid, 256, 0, stream>>>(
        (const u32*)hs2, rowStart, csrSrc, phaseOff, dinv, b2, out);
}

// Round 7
// 482.023 us; speedup vs baseline: 1.0223x; 1.0223x over previous
//
#include <hip/hip_runtime.h>

#define N_NODES 100000
#define IN_CH 128
#define HID 75
#define OUT_CH 40
#define N_EDGES 3200000

#define NB 196          // buckets of 512 dst nodes
#define CAP 20000       // per-bucket capacity; mean 16384
#define EPT 16          // edges per thread in passA
#define PA_EDGES (EPT * 256)

#define CH_STRIDE_U16 1600512   // 100032*16 u16 per feature-chunk table
#define CH_STRIDE_U32 800256

typedef unsigned short u16;
typedef unsigned int u32;
typedef unsigned long long u64;
typedef short short8 __attribute__((ext_vector_type(8)));
typedef float f32x4 __attribute__((ext_vector_type(4)));

__device__ __forceinline__ u16 f2bf(float f) {
    u32 b = __float_as_uint(f);
    b += 0x7FFF + ((b >> 16) & 1);   // round-to-nearest-even
    return (u16)(b >> 16);
}

// ---------------- edge-index layout probe (int32 vs int64) ----------------
__global__ void probe64(const int* __restrict__ e, int* __restrict__ flag) {
    __shared__ int nonzero;
    if (threadIdx.x == 0) nonzero = 0;
    __syncthreads();
    int idx = threadIdx.x * 12497;              // < 3.2M
    if (e[2 * idx + 1] != 0) nonzero = 1;       // safe for both layouts
    __syncthreads();
    if (threadIdx.x == 0) *flag = (nonzero == 0) ? 1 : 0;
}

// zero bucket cursors + zero h1b K-pad (u32 cols 40..47, gemm2 reads them)
__global__ __launch_bounds__(256) void init_misc(int* __restrict__ bucketCursor,
        u32* __restrict__ h1b32) {
    int i = blockIdx.x * 256 + threadIdx.x;
    if (i < NB * 16) bucketCursor[i] = 0;
    if (i < 800000) {
        int node = i >> 3, q = i & 7;
        h1b32[node * 48 + 40 + q] = 0;
    }
}

// ---------------- pass A: bin edges into 196 dst-range buckets ------------
__global__ __launch_bounds__(256) void passA(const int* __restrict__ e,
        const int* __restrict__ flag, int* __restrict__ bucketCursor,
        unsigned* __restrict__ bucketBuf) {
    __shared__ int cnt[NB];
    __shared__ int base[NB];
    int t = threadIdx.x;
    for (int i = t; i < NB; i += 256) cnt[i] = 0;
    __syncthreads();
    bool w64 = (*flag != 0);
    int s_[EPT], d_[EPT];
    int eb = blockIdx.x * PA_EDGES + t;
#pragma unroll
    for (int k = 0; k < EPT; ++k) {
        int idx = eb + k * 256;
        int s = 0, d = -1;
        if (idx < N_EDGES) {
            if (w64) { s = e[2 * idx]; d = e[2 * (N_EDGES + idx)]; }
            else     { s = e[idx];     d = e[N_EDGES + idx]; }
            atomicAdd(&cnt[d >> 9], 1);
        }
        s_[k] = s; d_[k] = d;
    }
    __syncthreads();
    for (int i = t; i < NB; i += 256) {
        int c = cnt[i];
        base[i] = (c > 0) ? atomicAdd(&bucketCursor[i * 16], c) : 0;  // 64B-padded cursors
        cnt[i] = 0;
    }
    __syncthreads();
#pragma unroll
    for (int k = 0; k < EPT; ++k) {
        int d = d_[k];
        if (d >= 0) {
            int b = d >> 9;
            int off = atomicAdd(&cnt[b], 1);
            int pos = base[b] + off;
            if (pos < CAP)
                bucketBuf[(size_t)b * CAP + pos] =
                    ((unsigned)(d & 511) << 17) | (unsigned)s_[k];
        }
    }
}

// ---------------- scan of 196 bucket sizes -> bucket starts ---------------
__global__ __launch_bounds__(256) void scan196(const int* __restrict__ bucketCursor,
        int* __restrict__ bucketStart, int* __restrict__ rowStart) {
    __shared__ int a[256], b[256];
    int t = threadIdx.x;
    int v = (t < NB) ? bucketCursor[t * 16] : 0;
    a[t] = v;
    __syncthreads();
    int* pin = a; int* pout = b;
    for (int o = 1; o < 256; o <<= 1) {
        int nv = pin[t] + ((t >= o) ? pin[t - o] : 0);
        pout[t] = nv;
        __syncthreads();
        int* tmp = pin; pin = pout; pout = tmp;
    }
    if (t < NB) bucketStart[t] = pin[t] - v;  // exclusive
    if (t == 0) rowStart[N_NODES] = N_EDGES;
}

// ---------------- pass B: per-bucket CSR fill, all atomics in LDS ---------
__global__ __launch_bounds__(1024) void passB(const unsigned* __restrict__ bucketBuf,
        const int* __restrict__ bucketCursor, const int* __restrict__ bucketStart,
        int* __restrict__ csrSrc, int* __restrict__ rowStart, float* __restrict__ dinv) {
    __shared__ int cnt[512];
    __shared__ int sa[512], sb[512];
    int b = blockIdx.x;
    int t = threadIdx.x;
    int n = bucketCursor[b * 16];
    int start = bucketStart[b];
    if (t < 512) cnt[t] = 0;
    __syncthreads();
    const unsigned* buf = bucketBuf + (size_t)b * CAP;
    for (int i = t; i < n; i += 1024) atomicAdd(&cnt[buf[i] >> 17], 1);
    __syncthreads();
    if (t < 512) sa[t] = cnt[t];
    __syncthreads();
    int* pin = sa; int* pout = sb;
    for (int o = 1; o < 512; o <<= 1) {
        if (t < 512) pout[t] = pin[t] + ((t >= o) ? pin[t - o] : 0);
        __syncthreads();
        int* tmp = pin; pin = pout; pout = tmp;
    }
    int excl = 0;
    if (t < 512) {
        int deg = cnt[t];
        excl = pin[t] - deg;
        int node = b * 512 + t;
        if (node < N_NODES) {
            rowStart[node] = start + excl;
            dinv[node] = rsqrtf((float)deg + 1.0f);  // +1 self-loop
        }
    }
    __syncthreads();
    if (t < 512) cnt[t] = excl;   // LDS cursors
    __syncthreads();
    for (int i = t; i < n; i += 1024) {
        unsigned p = buf[i];
        int pos = atomicAdd(&cnt[p >> 17], 1);
        csrSrc[start + pos] = (int)(p & 0x1FFFF);
    }
}

// ---------------- prep: bf16 transposed weights ---------------------------
__global__ __launch_bounds__(256) void prep_w(const float* __restrict__ W1,
        const float* __restrict__ W2, u16* __restrict__ w1t, u16* __restrict__ w2t) {
    int g = blockIdx.x * 256 + threadIdx.x;
    int stride = gridDim.x * 256;
    for (int i = g; i < 80 * 128; i += stride) {
        int c = i >> 7, k = i & 127;
        w1t[i] = (c < HID) ? f2bf(W1[k * HID + c]) : (u16)0;
    }
    for (int i = g; i < 48 * 96; i += stride) {
        int c = i / 96, k = i - c * 96;
        w2t[i] = (c < OUT_CH && k < HID) ? f2bf(W2[k * OUT_CH + c]) : (u16)0;
    }
}

// ---------------- GEMM1 via MFMA -> chunk-major bf16 tables ---------------
// hs1c[chunk][node][16 u16], chunk = feature/16 (chunks 0..4, features 0..79)
__global__ __launch_bounds__(256) void gemm1_mfma(const float* __restrict__ x,
        const u16* __restrict__ w1t, const float* __restrict__ dinv,
        u16* __restrict__ hs1c) {
    __shared__ u16 Wl[80 * 136];   // pad 128->136 elems: bank-spread rows
    int t = threadIdx.x;
    {
        const u32* ws = (const u32*)w1t;
        u32* wd = (u32*)Wl;
        for (int i = t; i < 80 * 64; i += 256) {
            int r = i >> 6, c = i & 63;
            wd[r * 68 + c] = ws[i];
        }
    }
    __syncthreads();
    int wid = t >> 6, lane = t & 63;
    int bl = lane & 15, kh = lane >> 4;
    int row0 = blockIdx.x * 64 + wid * 16;
    short8 bf[5][4];
#pragma unroll
    for (int ct = 0; ct < 5; ++ct)
#pragma unroll
        for (int ks = 0; ks < 4; ++ks)
            bf[ct][ks] = *(const short8*)&Wl[(ct * 16 + bl) * 136 + ks * 32 + kh * 8];
    f32x4 zero = {0.f, 0.f, 0.f, 0.f};
    f32x4 acc[5];
#pragma unroll
    for (int ct = 0; ct < 5; ++ct) acc[ct] = zero;
    int arow = row0 + bl;
    bool av = (arow < N_NODES);
    const float* xr = x + (size_t)arow * IN_CH + kh * 8;
#pragma unroll
    for (int ks = 0; ks < 4; ++ks) {
        short8 af = {0, 0, 0, 0, 0, 0, 0, 0};
        if (av) {
            float4 lo = *(const float4*)(xr + ks * 32);
            float4 hi = *(const float4*)(xr + ks * 32 + 4);
            af[0] = (short)f2bf(lo.x); af[1] = (short)f2bf(lo.y);
            af[2] = (short)f2bf(lo.z); af[3] = (short)f2bf(lo.w);
            af[4] = (short)f2bf(hi.x); af[5] = (short)f2bf(hi.y);
            af[6] = (short)f2bf(hi.z); af[7] = (short)f2bf(hi.w);
        }
#pragma unroll
        for (int ct = 0; ct < 5; ++ct)
            acc[ct] = __builtin_amdgcn_mfma_f32_16x16x32_bf16(af, bf[ct][ks], acc[ct], 0, 0, 0);
    }
    // C/D: col = lane&15, row = (lane>>4)*4 + reg  [HW-verified]
    int orow = row0 + kh * 4;
    float dn[4];
#pragma unroll
    for (int i = 0; i < 4; ++i) dn[i] = (orow + i < N_NODES) ? dinv[orow + i] : 0.f;
#pragma unroll
    for (int ct = 0; ct < 5; ++ct) {
#pragma unroll
        for (int i = 0; i < 4; ++i) {
            int r = orow + i;
            if (r < N_NODES)
                hs1c[(size_t)ct * CH_STRIDE_U16 + (size_t)r * 16 + bl] =
                    f2bf(acc[ct][i] * dn[i]);
        }
    }
}

// ---------------- GEMM2 via MFMA: hs2 = bf16(dinv * (h1 @ W2)), stride 48 -
__global__ __launch_bounds__(256) void gemm2_mfma(const u16* __restrict__ h1b,
        const u16* __restrict__ w2t, const float* __restrict__ dinv,
        u16* __restrict__ hs2) {
    __shared__ u16 Wl[48 * 104];   // pad 96->104
    int t = threadIdx.x;
    {
        const u32* ws = (const u32*)w2t;
        u32* wd = (u32*)Wl;
        for (int i = t; i < 48 * 48; i += 256) {
            int r = i / 48, c = i - r * 48;
            wd[r * 52 + c] = ws[i];
        }
    }
    __syncthreads();
    int wid = t >> 6, lane = t & 63;
    int bl = lane & 15, kh = lane >> 4;
    int row0 = blockIdx.x * 64 + wid * 16;
    short8 bf[3][3];
#pragma unroll
    for (int ct = 0; ct < 3; ++ct)
#pragma unroll
        for (int ks = 0; ks < 3; ++ks)
            bf[ct][ks] = *(const short8*)&Wl[(ct * 16 + bl) * 104 + ks * 32 + kh * 8];
    f32x4 zero = {0.f, 0.f, 0.f, 0.f};
    f32x4 acc[3];
#pragma unroll
    for (int ct = 0; ct < 3; ++ct) acc[ct] = zero;
    int arow = row0 + bl;
    bool av = (arow < N_NODES);
    const u16* hr = h1b + (size_t)arow * 96 + kh * 8;
#pragma unroll
    for (int ks = 0; ks < 3; ++ks) {
        short8 af = {0, 0, 0, 0, 0, 0, 0, 0};
        if (av) af = *(const short8*)(hr + ks * 32);
#pragma unroll
        for (int ct = 0; ct < 3; ++ct)
            acc[ct] = __builtin_amdgcn_mfma_f32_16x16x32_bf16(af, bf[ct][ks], acc[ct], 0, 0, 0);
    }
    int orow = row0 + kh * 4;
    float dn[4];
#pragma unroll
    for (int i = 0; i < 4; ++i) dn[i] = (orow + i < N_NODES) ? dinv[orow + i] : 0.f;
#pragma unroll
    for (int ct = 0; ct < 3; ++ct) {
        int col = ct * 16 + bl;
#pragma unroll
        for (int i = 0; i < 4; ++i) {
            int r = orow + i;
            if (r < N_NODES) hs2[(size_t)r * 48 + col] = f2bf(acc[ct][i] * dn[i]);
        }
    }
}

// ---------------- agg layer 1, one feature-chunk (32B rows, 3.2MB table) --
// wave-per-node; lane = (slot:3 | u:3): slot = edge within group of 8,
// u = u32 within chunk row. Register accum, shfl_xor reduce over slots.
__global__ __launch_bounds__(256) void agg1_chunk(
        const u32* __restrict__ tabc, const int* __restrict__ rowStart,
        const int* __restrict__ csrSrc, const float* __restrict__ dinv,
        const float* __restrict__ bias, u32* __restrict__ out,
        int coff, int fbase) {
    int wid = threadIdx.x >> 6, lane = threadIdx.x & 63;
    int node = blockIdx.x * 4 + wid;
    if (node >= N_NODES) return;
    int slot = lane >> 3, u = lane & 7;
    int rs = rowStart[node];
    int deg = rowStart[node + 1] - rs;
    float accLo = 0.f, accHi = 0.f;
    int niter = min(deg >> 3, 8);
    int idxs[8];
#pragma unroll
    for (int i = 0; i < 8; ++i)
        idxs[i] = (i < niter) ? csrSrc[rs + i * 8 + slot] : 0;
#pragma unroll
    for (int i = 0; i < 8; ++i) {
        if (i < niter) {
            u32 v = tabc[(size_t)idxs[i] * 8 + u];
            accLo += __uint_as_float(v << 16);
            accHi += __uint_as_float(v & 0xFFFF0000u);
        }
    }
    for (int j = niter * 8 + slot; j < deg; j += 8) {   // tail + deg>64
        int idx = csrSrc[rs + j];
        u32 v = tabc[(size_t)idx * 8 + u];
        accLo += __uint_as_float(v << 16);
        accHi += __uint_as_float(v & 0xFFFF0000u);
    }
#pragma unroll
    for (int o = 8; o < 64; o <<= 1) {                  // reduce 8 slots
        accLo += __shfl_xor(accLo, o);
        accHi += __shfl_xor(accHi, o);
    }
    {
        u32 v = tabc[(size_t)node * 8 + u];             // self-loop term
        accLo += __uint_as_float(v << 16);
        accHi += __uint_as_float(v & 0xFFFF0000u);
    }
    if (lane < 8) {                                     // u == lane here
        float dn = dinv[node];
        int f0 = fbase + 2 * lane, f1 = f0 + 1;
        float rlo = (f0 < HID) ? fmaxf(fmaf(dn, accLo, bias[f0]), 0.f) : 0.f;
        float rhi = (f1 < HID) ? fmaxf(fmaf(dn, accHi, bias[f1]), 0.f) : 0.f;
        out[(size_t)node * 48 + coff + lane] = ((u32)f2bf(rhi) << 16) | (u32)f2bf(rlo);
    }
}

// ---------------- aggregation layer 2 + log_softmax (lean R4 form) --------
__global__ __launch_bounds__(256) void aggregate2(
        const u32* __restrict__ tab, const int* __restrict__ rowStart,
        const int* __restrict__ csrSrc, const float* __restrict__ dinv,
        const float* __restrict__ bias, float* __restrict__ out) {
    int wid = threadIdx.x >> 6;
    int lane = threadIdx.x & 63;
    int node = __builtin_amdgcn_readfirstlane(blockIdx.x * 4 + wid);
    if (node >= N_NODES) return;
    bool act = lane < 20;
    float accLo = 0.f, accHi = 0.f;
    if (act) {
        u32 v = tab[(size_t)node * 24 + lane];        // self-loop term
        accLo = __uint_as_float(v << 16);
        accHi = __uint_as_float(v & 0xFFFF0000u);
    }
    int j = rowStart[node];
    int end = rowStart[node + 1];
    for (; j + 8 <= end; j += 8) {
        u32 v[8];
#pragma unroll
        for (int q = 0; q < 8; ++q) {
            int idx = csrSrc[j + q];                  // uniform -> s_load
            v[q] = act ? tab[(size_t)idx * 24 + lane] : 0u;
        }
#pragma unroll
        for (int q = 0; q < 8; ++q) {
            accLo += __uint_as_float(v[q] << 16);
            accHi += __uint_as_float(v[q] & 0xFFFF0000u);
        }
    }
    for (; j < end; ++j) {
        int idx = csrSrc[j];
        u32 v = act ? tab[(size_t)idx * 24 + lane] : 0u;
        accLo += __uint_as_float(v << 16);
        accHi += __uint_as_float(v & 0xFFFF0000u);
    }
    float dn = dinv[node];
    float vlo = 0.f, vhi = 0.f, m = -3.4e38f;
    if (act) {
        vlo = fmaf(dn, accLo, bias[2 * lane]);
        vhi = fmaf(dn, accHi, bias[2 * lane + 1]);
        m = fmaxf(vlo, vhi);
    }
#pragma unroll
    for (int o = 32; o > 0; o >>= 1) m = fmaxf(m, __shfl_xor(m, o));
    float e = act ? (expf(vlo - m) + expf(vhi - m)) : 0.f;
#pragma unroll
    for (int o = 32; o > 0; o >>= 1) e += __shfl_xor(e, o);
    float lse = logf(e);
    if (act) {
        float2 r = make_float2(vlo - m - lse, vhi - m - lse);
        *reinterpret_cast<float2*>(out + (size_t)node * OUT_CH + 2 * lane) = r;
    }
}

extern "C" void kernel_launch(void* const* d_in, const int* in_sizes, int n_in,
                              void* d_out, int out_size, void* d_ws, size_t ws_size,
                              hipStream_t stream) {
    const float* x  = (const float*)d_in[0];
    const int*   e  = (const int*)d_in[1];
    const float* W1 = (const float*)d_in[2];
    const float* b1 = (const float*)d_in[3];
    const float* W2 = (const float*)d_in[4];
    const float* b2 = (const float*)d_in[5];
    float* out = (float*)d_out;

    // workspace carve (all sizes multiples of 16 B); total ~59 MB
    char* w = (char*)d_ws;
    unsigned* bucketBuf = (unsigned*)w;               // 15.68 MB, dead after passB
    u16* hs1c = (u16*)w; w += (size_t)5 * CH_STRIDE_U16 * 2 + 512;  // 16.0 MB (aliases bucketBuf)
    u16* h1b  = (u16*)w; w += (size_t)100032 * 96 * 2;   // 19.2 MB
    int* csrSrc = (int*)w; w += (size_t)N_EDGES * 4;     // 12.8 MB
    u16* hs2  = (u16*)w; w += (size_t)100000 * 48 * 2;   // 9.6 MB
    int* rowStart = (int*)w; w += 400016;
    float* dinv   = (float*)w; w += 400000;
    int* bucketCursor = (int*)w; w += NB * 16 * 4;
    int* bucketStart  = (int*)w; w += 1024;
    u16* w1t = (u16*)w; w += 80 * 128 * 2;
    u16* w2t = (u16*)w; w += 48 * 96 * 2;
    int* flag = (int*)w; w += 16;

    probe64<<<1, 256, 0, stream>>>(e, flag);
    init_misc<<<3126, 256, 0, stream>>>(bucketCursor, (u32*)h1b);
    passA<<<(N_EDGES + PA_EDGES - 1) / PA_EDGES, 256, 0, stream>>>(
        e, flag, bucketCursor, bucketBuf);
    scan196<<<1, 256, 0, stream>>>(bucketCursor, bucketStart, rowStart);
    passB<<<NB, 1024, 0, stream>>>(bucketBuf, bucketCursor, bucketStart,
                                   csrSrc, rowStart, dinv);
    prep_w<<<16, 256, 0, stream>>>(W1, W2, w1t, w2t);

    gemm1_mfma<<<(N_NODES + 63) / 64, 256, 0, stream>>>(x, w1t, dinv, hs1c);
    for (int c = 0; c < 5; ++c)
        agg1_chunk<<<(N_NODES + 3) / 4, 256, 0, stream>>>(
            (const u32*)hs1c + (size_t)c * CH_STRIDE_U32, rowStart, csrSrc,
            dinv, b1, (u32*)h1b, 8 * c, 16 * c);
    gemm2_mfma<<<(N_NODES + 63) / 64, 256, 0, stream>>>(h1b, w2t, dinv, hs2);
    aggregate2<<<(N_NODES + 3) / 4, 256, 0, stream>>>(
        (const u32*)hs2, rowStart, csrSrc, dinv, b2, out);
}

// Round 8
// 304.436 us; speedup vs baseline: 1.6187x; 1.5833x over previous
//
#include <hip/hip_runtime.h>

#define N_NODES 100000
#define IN_CH 128
#define HID 75
#define OUT_CH 40
#define N_EDGES 3200000

#define NB 196          // buckets of 512 dst nodes
#define CAP 20000       // per-bucket capacity; mean 16384
#define EPT 16          // edges per thread in passA
#define PA_EDGES (EPT * 256)

typedef unsigned short u16;
typedef unsigned int u32;
typedef short short8 __attribute__((ext_vector_type(8)));
typedef float f32x4 __attribute__((ext_vector_type(4)));

__device__ __forceinline__ u16 f2bf(float f) {
    u32 b = __float_as_uint(f);
    b += 0x7FFF + ((b >> 16) & 1);   // round-to-nearest-even
    return (u16)(b >> 16);
}

// ---------------- edge-index layout probe (int32 vs int64) ----------------
__global__ void probe64(const int* __restrict__ e, int* __restrict__ flag) {
    __shared__ int nonzero;
    if (threadIdx.x == 0) nonzero = 0;
    __syncthreads();
    int idx = threadIdx.x * 12497;              // < 3.2M
    if (e[2 * idx + 1] != 0) nonzero = 1;       // safe for both layouts
    __syncthreads();
    if (threadIdx.x == 0) *flag = (nonzero == 0) ? 1 : 0;
}

// zero bucket cursors + zero h1b K-pad (u32 cols 40..47; gemm2 reads them)
__global__ __launch_bounds__(256) void init_misc(int* __restrict__ bucketCursor,
        u32* __restrict__ h1b32) {
    int i = blockIdx.x * 256 + threadIdx.x;
    if (i < NB * 16) bucketCursor[i] = 0;
    if (i < 800000) {
        int node = i >> 3, q = i & 7;
        h1b32[node * 48 + 40 + q] = 0;
    }
}

// ---------------- pass A: bin edges into 196 dst-range buckets ------------
__global__ __launch_bounds__(256) void passA(const int* __restrict__ e,
        const int* __restrict__ flag, int* __restrict__ bucketCursor,
        unsigned* __restrict__ bucketBuf) {
    __shared__ int cnt[NB];
    __shared__ int base[NB];
    int t = threadIdx.x;
    for (int i = t; i < NB; i += 256) cnt[i] = 0;
    __syncthreads();
    bool w64 = (*flag != 0);
    int s_[EPT], d_[EPT];
    int eb = blockIdx.x * PA_EDGES + t;
#pragma unroll
    for (int k = 0; k < EPT; ++k) {
        int idx = eb + k * 256;
        int s = 0, d = -1;
        if (idx < N_EDGES) {
            if (w64) { s = e[2 * idx]; d = e[2 * (N_EDGES + idx)]; }
            else     { s = e[idx];     d = e[N_EDGES + idx]; }
            atomicAdd(&cnt[d >> 9], 1);
        }
        s_[k] = s; d_[k] = d;
    }
    __syncthreads();
    for (int i = t; i < NB; i += 256) {
        int c = cnt[i];
        base[i] = (c > 0) ? atomicAdd(&bucketCursor[i * 16], c) : 0;  // 64B-padded cursors
        cnt[i] = 0;
    }
    __syncthreads();
#pragma unroll
    for (int k = 0; k < EPT; ++k) {
        int d = d_[k];
        if (d >= 0) {
            int b = d >> 9;
            int off = atomicAdd(&cnt[b], 1);
            int pos = base[b] + off;
            if (pos < CAP)
                bucketBuf[(size_t)b * CAP + pos] =
                    ((unsigned)(d & 511) << 17) | (unsigned)s_[k];
        }
    }
}

// ---------------- scan of 196 bucket sizes -> bucket starts ---------------
__global__ __launch_bounds__(256) void scan196(const int* __restrict__ bucketCursor,
        int* __restrict__ bucketStart, int* __restrict__ rowStart) {
    __shared__ int a[256], b[256];
    int t = threadIdx.x;
    int v = (t < NB) ? bucketCursor[t * 16] : 0;
    a[t] = v;
    __syncthreads();
    int* pin = a; int* pout = b;
    for (int o = 1; o < 256; o <<= 1) {
        int nv = pin[t] + ((t >= o) ? pin[t - o] : 0);
        pout[t] = nv;
        __syncthreads();
        int* tmp = pin; pin = pout; pout = tmp;
    }
    if (t < NB) bucketStart[t] = pin[t] - v;  // exclusive
    if (t == 0) rowStart[N_NODES] = N_EDGES;
}

// ---------------- pass B: per-bucket CSR fill, all atomics in LDS ---------
__global__ __launch_bounds__(1024) void passB(const unsigned* __restrict__ bucketBuf,
        const int* __restrict__ bucketCursor, const int* __restrict__ bucketStart,
        int* __restrict__ csrSrc, int* __restrict__ rowStart, float* __restrict__ dinv) {
    __shared__ int cnt[512];
    __shared__ int sa[512], sb[512];
    int b = blockIdx.x;
    int t = threadIdx.x;
    int n = bucketCursor[b * 16];
    int start = bucketStart[b];
    if (t < 512) cnt[t] = 0;
    __syncthreads();
    const unsigned* buf = bucketBuf + (size_t)b * CAP;
    for (int i = t; i < n; i += 1024) atomicAdd(&cnt[buf[i] >> 17], 1);
    __syncthreads();
    if (t < 512) sa[t] = cnt[t];
    __syncthreads();
    int* pin = sa; int* pout = sb;
    for (int o = 1; o < 512; o <<= 1) {
        if (t < 512) pout[t] = pin[t] + ((t >= o) ? pin[t - o] : 0);
        __syncthreads();
        int* tmp = pin; pin = pout; pout = tmp;
    }
    int excl = 0;
    if (t < 512) {
        int deg = cnt[t];
        excl = pin[t] - deg;
        int node = b * 512 + t;
        if (node < N_NODES) {
            rowStart[node] = start + excl;
            dinv[node] = rsqrtf((float)deg + 1.0f);  // +1 self-loop
        }
    }
    __syncthreads();
    if (t < 512) cnt[t] = excl;   // LDS cursors
    __syncthreads();
    for (int i = t; i < n; i += 1024) {
        unsigned p = buf[i];
        int pos = atomicAdd(&cnt[p >> 17], 1);
        csrSrc[start + pos] = (int)(p & 0x1FFFF);
    }
}

// ---------------- prep: bf16 transposed weights ---------------------------
__global__ __launch_bounds__(256) void prep_w(const float* __restrict__ W1,
        const float* __restrict__ W2, u16* __restrict__ w1t, u16* __restrict__ w2t) {
    int g = blockIdx.x * 256 + threadIdx.x;
    int stride = gridDim.x * 256;
    for (int i = g; i < 80 * 128; i += stride) {
        int c = i >> 7, k = i & 127;
        w1t[i] = (c < HID) ? f2bf(W1[k * HID + c]) : (u16)0;
    }
    for (int i = g; i < 48 * 96; i += stride) {
        int c = i / 96, k = i - c * 96;
        w2t[i] = (c < OUT_CH && k < HID) ? f2bf(W2[k * OUT_CH + c]) : (u16)0;
    }
}

// ---------------- GEMM1 via MFMA -> split tables --------------------------
// hsA[node][64 u16] (feats 0..63, 128B rows), hsB[node][16 u16] (feats 64..79,
// 32B rows; 75..79 are zero since w1t cols are zero-padded)
__global__ __launch_bounds__(256) void gemm1_mfma(const float* __restrict__ x,
        const u16* __restrict__ w1t, const float* __restrict__ dinv,
        u16* __restrict__ hsA, u16* __restrict__ hsB) {
    __shared__ u16 Wl[80 * 136];   // pad 128->136 elems: bank-spread rows
    int t = threadIdx.x;
    {
        const u32* ws = (const u32*)w1t;
        u32* wd = (u32*)Wl;
        for (int i = t; i < 80 * 64; i += 256) {
            int r = i >> 6, c = i & 63;
            wd[r * 68 + c] = ws[i];
        }
    }
    __syncthreads();
    int wid = t >> 6, lane = t & 63;
    int bl = lane & 15, kh = lane >> 4;
    int row0 = blockIdx.x * 64 + wid * 16;
    short8 bf[5][4];
#pragma unroll
    for (int ct = 0; ct < 5; ++ct)
#pragma unroll
        for (int ks = 0; ks < 4; ++ks)
            bf[ct][ks] = *(const short8*)&Wl[(ct * 16 + bl) * 136 + ks * 32 + kh * 8];
    f32x4 zero = {0.f, 0.f, 0.f, 0.f};
    f32x4 acc[5];
#pragma unroll
    for (int ct = 0; ct < 5; ++ct) acc[ct] = zero;
    int arow = row0 + bl;
    bool av = (arow < N_NODES);
    const float* xr = x + (size_t)arow * IN_CH + kh * 8;
#pragma unroll
    for (int ks = 0; ks < 4; ++ks) {
        short8 af = {0, 0, 0, 0, 0, 0, 0, 0};
        if (av) {
            float4 lo = *(const float4*)(xr + ks * 32);
            float4 hi = *(const float4*)(xr + ks * 32 + 4);
            af[0] = (short)f2bf(lo.x); af[1] = (short)f2bf(lo.y);
            af[2] = (short)f2bf(lo.z); af[3] = (short)f2bf(lo.w);
            af[4] = (short)f2bf(hi.x); af[5] = (short)f2bf(hi.y);
            af[6] = (short)f2bf(hi.z); af[7] = (short)f2bf(hi.w);
        }
#pragma unroll
        for (int ct = 0; ct < 5; ++ct)
            acc[ct] = __builtin_amdgcn_mfma_f32_16x16x32_bf16(af, bf[ct][ks], acc[ct], 0, 0, 0);
    }
    // C/D: col = lane&15, row = (lane>>4)*4 + reg  [HW-verified]
    int orow = row0 + kh * 4;
    float dn[4];
#pragma unroll
    for (int i = 0; i < 4; ++i) dn[i] = (orow + i < N_NODES) ? dinv[orow + i] : 0.f;
#pragma unroll
    for (int ct = 0; ct < 5; ++ct) {
        int col = ct * 16 + bl;
#pragma unroll
        for (int i = 0; i < 4; ++i) {
            int r = orow + i;
            if (r < N_NODES) {
                u16 val = f2bf(acc[ct][i] * dn[i]);
                if (ct < 4) hsA[(size_t)r * 64 + col] = val;
                else        hsB[(size_t)r * 16 + (col - 64)] = val;
            }
        }
    }
}

// ---------------- GEMM2 via MFMA -> split tables --------------------------
// hs2A[node][32 u16] (feats 0..31, 64B rows), hs2B[node][8 u16] (feats 32..39)
__global__ __launch_bounds__(256) void gemm2_mfma(const u16* __restrict__ h1b,
        const u16* __restrict__ w2t, const float* __restrict__ dinv,
        u16* __restrict__ hs2A, u16* __restrict__ hs2B) {
    __shared__ u16 Wl[48 * 104];   // pad 96->104
    int t = threadIdx.x;
    {
        const u32* ws = (const u32*)w2t;
        u32* wd = (u32*)Wl;
        for (int i = t; i < 48 * 48; i += 256) {
            int r = i / 48, c = i - r * 48;
            wd[r * 52 + c] = ws[i];
        }
    }
    __syncthreads();
    int wid = t >> 6, lane = t & 63;
    int bl = lane & 15, kh = lane >> 4;
    int row0 = blockIdx.x * 64 + wid * 16;
    short8 bf[3][3];
#pragma unroll
    for (int ct = 0; ct < 3; ++ct)
#pragma unroll
        for (int ks = 0; ks < 3; ++ks)
            bf[ct][ks] = *(const short8*)&Wl[(ct * 16 + bl) * 104 + ks * 32 + kh * 8];
    f32x4 zero = {0.f, 0.f, 0.f, 0.f};
    f32x4 acc[3];
#pragma unroll
    for (int ct = 0; ct < 3; ++ct) acc[ct] = zero;
    int arow = row0 + bl;
    bool av = (arow < N_NODES);
    const u16* hr = h1b + (size_t)arow * 96 + kh * 8;
#pragma unroll
    for (int ks = 0; ks < 3; ++ks) {
        short8 af = {0, 0, 0, 0, 0, 0, 0, 0};
        if (av) af = *(const short8*)(hr + ks * 32);
#pragma unroll
        for (int ct = 0; ct < 3; ++ct)
            acc[ct] = __builtin_amdgcn_mfma_f32_16x16x32_bf16(af, bf[ct][ks], acc[ct], 0, 0, 0);
    }
    int orow = row0 + kh * 4;
    float dn[4];
#pragma unroll
    for (int i = 0; i < 4; ++i) dn[i] = (orow + i < N_NODES) ? dinv[orow + i] : 0.f;
#pragma unroll
    for (int ct = 0; ct < 3; ++ct) {
        int col = ct * 16 + bl;
#pragma unroll
        for (int i = 0; i < 4; ++i) {
            int r = orow + i;
            if (r < N_NODES) {
                u16 val = f2bf(acc[ct][i] * dn[i]);
                if (ct < 2)          hs2A[(size_t)r * 32 + col] = val;
                else if (bl < 8)     hs2B[(size_t)r * 8 + (col - 32)] = val;
            }
        }
    }
}

// ---------------- aggregation layer 1: split-table gather -----------------
// lanes 0..31 gather hsA (u32, feats 2l,2l+1); lanes 32..39 gather hsB.
// One predicated gather instr/edge (per-lane address select). f0 = 2*lane.
__global__ __launch_bounds__(256) void aggregate1(
        const u32* __restrict__ tabA, const u32* __restrict__ tabB,
        const int* __restrict__ rowStart, const int* __restrict__ csrSrc,
        const float* __restrict__ dinv, const float* __restrict__ bias,
        u32* __restrict__ out) {
    int wid = threadIdx.x >> 6;
    int lane = threadIdx.x & 63;
    int node = __builtin_amdgcn_readfirstlane(blockIdx.x * 4 + wid);
    if (node >= N_NODES) return;
    bool act = lane < 40;
    const u32* base = (lane < 32) ? (tabA + lane) : (tabB + (lane - 32));
    int sh = (lane < 32) ? 5 : 3;                    // row stride 32 or 8 u32
    float accLo = 0.f, accHi = 0.f;
    if (act) {
        u32 v = base[(size_t)node << sh];            // self-loop term
        accLo = __uint_as_float(v << 16);
        accHi = __uint_as_float(v & 0xFFFF0000u);
    }
    int j = rowStart[node];
    int end = rowStart[node + 1];
    for (; j + 8 <= end; j += 8) {
        u32 v[8];
#pragma unroll
        for (int q = 0; q < 8; ++q) {
            int idx = csrSrc[j + q];                 // uniform -> s_load
            v[q] = act ? base[(size_t)idx << sh] : 0u;
        }
#pragma unroll
        for (int q = 0; q < 8; ++q) {
            accLo += __uint_as_float(v[q] << 16);
            accHi += __uint_as_float(v[q] & 0xFFFF0000u);
        }
    }
    for (; j < end; ++j) {
        int idx = csrSrc[j];
        u32 v = act ? base[(size_t)idx << sh] : 0u;
        accLo += __uint_as_float(v << 16);
        accHi += __uint_as_float(v & 0xFFFF0000u);
    }
    float dn = dinv[node];
    int f0 = 2 * lane, f1 = f0 + 1;                  // holds for both groups
    float blo = (f0 < HID) ? bias[f0] : 0.f;
    float bhi = (f1 < HID) ? bias[f1] : 0.f;
    float rlo = (f0 < HID) ? fmaxf(fmaf(dn, accLo, blo), 0.f) : 0.f;
    float rhi = (f1 < HID) ? fmaxf(fmaf(dn, accHi, bhi), 0.f) : 0.f;
    if (act)
        out[(size_t)node * 48 + lane] = ((u32)f2bf(rhi) << 16) | (u32)f2bf(rlo);
}

// ---------------- aggregation layer 2 + log_softmax (split tables) --------
// lanes 0..15 gather hs2A; lanes 16..19 gather hs2B. f0 = 2*lane both groups.
__global__ __launch_bounds__(256) void aggregate2(
        const u32* __restrict__ tabA, const u32* __restrict__ tabB,
        const int* __restrict__ rowStart, const int* __restrict__ csrSrc,
        const float* __restrict__ dinv, const float* __restrict__ bias,
        float* __restrict__ out) {
    int wid = threadIdx.x >> 6;
    int lane = threadIdx.x & 63;
    int node = __builtin_amdgcn_readfirstlane(blockIdx.x * 4 + wid);
    if (node >= N_NODES) return;
    bool act = lane < 20;
    const u32* base = (lane < 16) ? (tabA + lane) : (tabB + (lane - 16));
    int sh = (lane < 16) ? 4 : 2;                    // row stride 16 or 4 u32
    float accLo = 0.f, accHi = 0.f;
    if (act) {
        u32 v = base[(size_t)node << sh];            // self-loop term
        accLo = __uint_as_float(v << 16);
        accHi = __uint_as_float(v & 0xFFFF0000u);
    }
    int j = rowStart[node];
    int end = rowStart[node + 1];
    for (; j + 8 <= end; j += 8) {
        u32 v[8];
#pragma unroll
        for (int q = 0; q < 8; ++q) {
            int idx = csrSrc[j + q];                 // uniform -> s_load
            v[q] = act ? base[(size_t)idx << sh] : 0u;
        }
#pragma unroll
        for (int q = 0; q < 8; ++q) {
            accLo += __uint_as_float(v[q] << 16);
            accHi += __uint_as_float(v[q] & 0xFFFF0000u);
        }
    }
    for (; j < end; ++j) {
        int idx = csrSrc[j];
        u32 v = act ? base[(size_t)idx << sh] : 0u;
        accLo += __uint_as_float(v << 16);
        accHi += __uint_as_float(v & 0xFFFF0000u);
    }
    float dn = dinv[node];
    float vlo = 0.f, vhi = 0.f, m = -3.4e38f;
    if (act) {
        vlo = fmaf(dn, accLo, bias[2 * lane]);
        vhi = fmaf(dn, accHi, bias[2 * lane + 1]);
        m = fmaxf(vlo, vhi);
    }
#pragma unroll
    for (int o = 32; o > 0; o >>= 1) m = fmaxf(m, __shfl_xor(m, o));
    float e = act ? (expf(vlo - m) + expf(vhi - m)) : 0.f;
#pragma unroll
    for (int o = 32; o > 0; o >>= 1) e += __shfl_xor(e, o);
    float lse = logf(e);
    if (act) {
        float2 r = make_float2(vlo - m - lse, vhi - m - lse);
        *reinterpret_cast<float2*>(out + (size_t)node * OUT_CH + 2 * lane) = r;
    }
}

extern "C" void kernel_launch(void* const* d_in, const int* in_sizes, int n_in,
                              void* d_out, int out_size, void* d_ws, size_t ws_size,
                              hipStream_t stream) {
    const float* x  = (const float*)d_in[0];
    const int*   e  = (const int*)d_in[1];
    const float* W1 = (const float*)d_in[2];
    const float* b1 = (const float*)d_in[3];
    const float* W2 = (const float*)d_in[4];
    const float* b2 = (const float*)d_in[5];
    float* out = (float*)d_out;

    // workspace carve (all sizes multiples of 16 B); total ~59 MB
    char* w = (char*)d_ws;
    unsigned* bucketBuf = (unsigned*)w;                  // 15.68 MB, dead after passB
    u16* hsA = (u16*)w; w += (size_t)100032 * 64 * 2;    // 12.80 MB (aliases bucketBuf)
    u16* hsB = (u16*)w; w += (size_t)100032 * 16 * 2;    // 3.20 MB  (aliases bucketBuf)
    u16* h1b  = (u16*)w; w += (size_t)100032 * 96 * 2;   // 19.2 MB
    int* csrSrc = (int*)w; w += (size_t)N_EDGES * 4;     // 12.8 MB
    u16* hs2A = (u16*)w; w += (size_t)100032 * 32 * 2;   // 6.40 MB (offset 64B-aligned)
    u16* hs2B = (u16*)w; w += (size_t)100032 * 8 * 2;    // 1.60 MB
    int* rowStart = (int*)w; w += 400016;
    float* dinv   = (float*)w; w += 400000;
    int* bucketCursor = (int*)w; w += NB * 16 * 4;
    int* bucketStart  = (int*)w; w += 1024;
    u16* w1t = (u16*)w; w += 80 * 128 * 2;
    u16* w2t = (u16*)w; w += 48 * 96 * 2;
    int* flag = (int*)w; w += 16;

    probe64<<<1, 256, 0, stream>>>(e, flag);
    init_misc<<<3126, 256, 0, stream>>>(bucketCursor, (u32*)h1b);
    passA<<<(N_EDGES + PA_EDGES - 1) / PA_EDGES, 256, 0, stream>>>(
        e, flag, bucketCursor, bucketBuf);
    scan196<<<1, 256, 0, stream>>>(bucketCursor, bucketStart, rowStart);
    passB<<<NB, 1024, 0, stream>>>(bucketBuf, bucketCursor, bucketStart,
                                   csrSrc, rowStart, dinv);
    prep_w<<<16, 256, 0, stream>>>(W1, W2, w1t, w2t);

    gemm1_mfma<<<(N_NODES + 63) / 64, 256, 0, stream>>>(x, w1t, dinv, hsA, hsB);
    aggregate1<<<(N_NODES + 3) / 4, 256, 0, stream>>>(
        (const u32*)hsA, (const u32*)hsB, rowStart, csrSrc, dinv, b1, (u32*)h1b);
    gemm2_mfma<<<(N_NODES + 63) / 64, 256, 0, stream>>>(h1b, w2t, dinv, hs2A, hs2B);
    aggregate2<<<(N_NODES + 3) / 4, 256, 0, stream>>>(
        (const u32*)hs2A, (const u32*)hs2B, rowStart, csrSrc, dinv, b2, out);
}

// Round 9
// 290.224 us; speedup vs baseline: 1.6979x; 1.0490x over previous
//
#include <hip/hip_runtime.h>

#define N_NODES 100000
#define IN_CH 128
#define HID 75
#define OUT_CH 40
#define N_EDGES 3200000

#define NB 196          // buckets of 512 dst nodes
#define CAP 20000       // per-bucket capacity; mean 16384
#define EPT 16          // edges per thread in passA
#define PA_EDGES (EPT * 256)

typedef unsigned short u16;
typedef unsigned int u32;
typedef short short8 __attribute__((ext_vector_type(8)));
typedef float f32x4 __attribute__((ext_vector_type(4)));
typedef u32 u32x2 __attribute__((ext_vector_type(2)));

__device__ __forceinline__ u16 f2bf(float f) {
    u32 b = __float_as_uint(f);
    b += 0x7FFF + ((b >> 16) & 1);   // round-to-nearest-even
    return (u16)(b >> 16);
}
__device__ __forceinline__ float uaf(u32 u) { return __uint_as_float(u); }

// ---------------- edge-index layout probe (int32 vs int64) ----------------
__global__ void probe64(const int* __restrict__ e, int* __restrict__ flag) {
    __shared__ int nonzero;
    if (threadIdx.x == 0) nonzero = 0;
    __syncthreads();
    int idx = threadIdx.x * 12497;              // < 3.2M
    if (e[2 * idx + 1] != 0) nonzero = 1;       // safe for both layouts
    __syncthreads();
    if (threadIdx.x == 0) *flag = (nonzero == 0) ? 1 : 0;
}

// zero bucket cursors + zero h1b K-pad (u32 cols 40..47; gemm2 reads them)
__global__ __launch_bounds__(256) void init_misc(int* __restrict__ bucketCursor,
        u32* __restrict__ h1b32) {
    int i = blockIdx.x * 256 + threadIdx.x;
    if (i < NB * 16) bucketCursor[i] = 0;
    if (i < 800000) {
        int node = i >> 3, q = i & 7;
        h1b32[node * 48 + 40 + q] = 0;
    }
}

// ---------------- pass A: bin edges into 196 dst-range buckets ------------
__global__ __launch_bounds__(256) void passA(const int* __restrict__ e,
        const int* __restrict__ flag, int* __restrict__ bucketCursor,
        unsigned* __restrict__ bucketBuf) {
    __shared__ int cnt[NB];
    __shared__ int base[NB];
    int t = threadIdx.x;
    for (int i = t; i < NB; i += 256) cnt[i] = 0;
    __syncthreads();
    bool w64 = (*flag != 0);
    int s_[EPT], d_[EPT];
    int eb = blockIdx.x * PA_EDGES + t;
#pragma unroll
    for (int k = 0; k < EPT; ++k) {
        int idx = eb + k * 256;
        int s = 0, d = -1;
        if (idx < N_EDGES) {
            if (w64) { s = e[2 * idx]; d = e[2 * (N_EDGES + idx)]; }
            else     { s = e[idx];     d = e[N_EDGES + idx]; }
            atomicAdd(&cnt[d >> 9], 1);
        }
        s_[k] = s; d_[k] = d;
    }
    __syncthreads();
    for (int i = t; i < NB; i += 256) {
        int c = cnt[i];
        base[i] = (c > 0) ? atomicAdd(&bucketCursor[i * 16], c) : 0;  // 64B-padded cursors
        cnt[i] = 0;
    }
    __syncthreads();
#pragma unroll
    for (int k = 0; k < EPT; ++k) {
        int d = d_[k];
        if (d >= 0) {
            int b = d >> 9;
            int off = atomicAdd(&cnt[b], 1);
            int pos = base[b] + off;
            if (pos < CAP)
                bucketBuf[(size_t)b * CAP + pos] =
                    ((unsigned)(d & 511) << 17) | (unsigned)s_[k];
        }
    }
}

// ---------------- scan of 196 bucket sizes -> bucket starts ---------------
__global__ __launch_bounds__(256) void scan196(const int* __restrict__ bucketCursor,
        int* __restrict__ bucketStart, int* __restrict__ rowStart) {
    __shared__ int a[256], b[256];
    int t = threadIdx.x;
    int v = (t < NB) ? bucketCursor[t * 16] : 0;
    a[t] = v;
    __syncthreads();
    int* pin = a; int* pout = b;
    for (int o = 1; o < 256; o <<= 1) {
        int nv = pin[t] + ((t >= o) ? pin[t - o] : 0);
        pout[t] = nv;
        __syncthreads();
        int* tmp = pin; pin = pout; pout = tmp;
    }
    if (t < NB) bucketStart[t] = pin[t] - v;  // exclusive
    if (t == 0) rowStart[N_NODES] = N_EDGES;
}

// ---------------- pass B: per-bucket CSR fill, all atomics in LDS ---------
__global__ __launch_bounds__(1024) void passB(const unsigned* __restrict__ bucketBuf,
        const int* __restrict__ bucketCursor, const int* __restrict__ bucketStart,
        int* __restrict__ csrSrc, int* __restrict__ rowStart, float* __restrict__ dinv) {
    __shared__ int cnt[512];
    __shared__ int sa[512], sb[512];
    int b = blockIdx.x;
    int t = threadIdx.x;
    int n = bucketCursor[b * 16];
    int start = bucketStart[b];
    if (t < 512) cnt[t] = 0;
    __syncthreads();
    const unsigned* buf = bucketBuf + (size_t)b * CAP;
    for (int i = t; i < n; i += 1024) atomicAdd(&cnt[buf[i] >> 17], 1);
    __syncthreads();
    if (t < 512) sa[t] = cnt[t];
    __syncthreads();
    int* pin = sa; int* pout = sb;
    for (int o = 1; o < 512; o <<= 1) {
        if (t < 512) pout[t] = pin[t] + ((t >= o) ? pin[t - o] : 0);
        __syncthreads();
        int* tmp = pin; pin = pout; pout = tmp;
    }
    int excl = 0;
    if (t < 512) {
        int deg = cnt[t];
        excl = pin[t] - deg;
        int node = b * 512 + t;
        if (node < N_NODES) {
            rowStart[node] = start + excl;
            dinv[node] = rsqrtf((float)deg + 1.0f);  // +1 self-loop
        }
    }
    __syncthreads();
    if (t < 512) cnt[t] = excl;   // LDS cursors
    __syncthreads();
    for (int i = t; i < n; i += 1024) {
        unsigned p = buf[i];
        int pos = atomicAdd(&cnt[p >> 17], 1);
        csrSrc[start + pos] = (int)(p & 0x1FFFF);
    }
}

// ---------------- prep: bf16 transposed weights ---------------------------
__global__ __launch_bounds__(256) void prep_w(const float* __restrict__ W1,
        const float* __restrict__ W2, u16* __restrict__ w1t, u16* __restrict__ w2t) {
    int g = blockIdx.x * 256 + threadIdx.x;
    int stride = gridDim.x * 256;
    for (int i = g; i < 80 * 128; i += stride) {
        int c = i >> 7, k = i & 127;
        w1t[i] = (c < HID) ? f2bf(W1[k * HID + c]) : (u16)0;
    }
    for (int i = g; i < 48 * 96; i += stride) {
        int c = i / 96, k = i - c * 96;
        w2t[i] = (c < OUT_CH && k < HID) ? f2bf(W2[k * OUT_CH + c]) : (u16)0;
    }
}

// ---------------- GEMM1 via MFMA -> split tables --------------------------
// hsA[node][64 u16] (feats 0..63, 128B rows), hsB[node][16 u16] (feats 64..79,
// 32B rows; 75..79 are zero since w1t cols are zero-padded)
__global__ __launch_bounds__(256) void gemm1_mfma(const float* __restrict__ x,
        const u16* __restrict__ w1t, const float* __restrict__ dinv,
        u16* __restrict__ hsA, u16* __restrict__ hsB) {
    __shared__ u16 Wl[80 * 136];   // pad 128->136 elems: bank-spread rows
    int t = threadIdx.x;
    {
        const u32* ws = (const u32*)w1t;
        u32* wd = (u32*)Wl;
        for (int i = t; i < 80 * 64; i += 256) {
            int r = i >> 6, c = i & 63;
            wd[r * 68 + c] = ws[i];
        }
    }
    __syncthreads();
    int wid = t >> 6, lane = t & 63;
    int bl = lane & 15, kh = lane >> 4;
    int row0 = blockIdx.x * 64 + wid * 16;
    short8 bf[5][4];
#pragma unroll
    for (int ct = 0; ct < 5; ++ct)
#pragma unroll
        for (int ks = 0; ks < 4; ++ks)
            bf[ct][ks] = *(const short8*)&Wl[(ct * 16 + bl) * 136 + ks * 32 + kh * 8];
    f32x4 zero = {0.f, 0.f, 0.f, 0.f};
    f32x4 acc[5];
#pragma unroll
    for (int ct = 0; ct < 5; ++ct) acc[ct] = zero;
    int arow = row0 + bl;
    bool av = (arow < N_NODES);
    const float* xr = x + (size_t)arow * IN_CH + kh * 8;
#pragma unroll
    for (int ks = 0; ks < 4; ++ks) {
        short8 af = {0, 0, 0, 0, 0, 0, 0, 0};
        if (av) {
            float4 lo = *(const float4*)(xr + ks * 32);
            float4 hi = *(const float4*)(xr + ks * 32 + 4);
            af[0] = (short)f2bf(lo.x); af[1] = (short)f2bf(lo.y);
            af[2] = (short)f2bf(lo.z); af[3] = (short)f2bf(lo.w);
            af[4] = (short)f2bf(hi.x); af[5] = (short)f2bf(hi.y);
            af[6] = (short)f2bf(hi.z); af[7] = (short)f2bf(hi.w);
        }
#pragma unroll
        for (int ct = 0; ct < 5; ++ct)
            acc[ct] = __builtin_amdgcn_mfma_f32_16x16x32_bf16(af, bf[ct][ks], acc[ct], 0, 0, 0);
    }
    // C/D: col = lane&15, row = (lane>>4)*4 + reg  [HW-verified]
    int orow = row0 + kh * 4;
    float dn[4];
#pragma unroll
    for (int i = 0; i < 4; ++i) dn[i] = (orow + i < N_NODES) ? dinv[orow + i] : 0.f;
#pragma unroll
    for (int ct = 0; ct < 5; ++ct) {
        int col = ct * 16 + bl;
#pragma unroll
        for (int i = 0; i < 4; ++i) {
            int r = orow + i;
            if (r < N_NODES) {
                u16 val = f2bf(acc[ct][i] * dn[i]);
                if (ct < 4) hsA[(size_t)r * 64 + col] = val;
                else        hsB[(size_t)r * 16 + (col - 64)] = val;
            }
        }
    }
}

// ---------------- GEMM2 via MFMA -> split tables --------------------------
// hs2A[node][32 u16] (feats 0..31, 64B rows), hs2B[node][8 u16] (feats 32..39)
__global__ __launch_bounds__(256) void gemm2_mfma(const u16* __restrict__ h1b,
        const u16* __restrict__ w2t, const float* __restrict__ dinv,
        u16* __restrict__ hs2A, u16* __restrict__ hs2B) {
    __shared__ u16 Wl[48 * 104];   // pad 96->104
    int t = threadIdx.x;
    {
        const u32* ws = (const u32*)w2t;
        u32* wd = (u32*)Wl;
        for (int i = t; i < 48 * 48; i += 256) {
            int r = i / 48, c = i - r * 48;
            wd[r * 52 + c] = ws[i];
        }
    }
    __syncthreads();
    int wid = t >> 6, lane = t & 63;
    int bl = lane & 15, kh = lane >> 4;
    int row0 = blockIdx.x * 64 + wid * 16;
    short8 bf[3][3];
#pragma unroll
    for (int ct = 0; ct < 3; ++ct)
#pragma unroll
        for (int ks = 0; ks < 3; ++ks)
            bf[ct][ks] = *(const short8*)&Wl[(ct * 16 + bl) * 104 + ks * 32 + kh * 8];
    f32x4 zero = {0.f, 0.f, 0.f, 0.f};
    f32x4 acc[3];
#pragma unroll
    for (int ct = 0; ct < 3; ++ct) acc[ct] = zero;
    int arow = row0 + bl;
    bool av = (arow < N_NODES);
    const u16* hr = h1b + (size_t)arow * 96 + kh * 8;
#pragma unroll
    for (int ks = 0; ks < 3; ++ks) {
        short8 af = {0, 0, 0, 0, 0, 0, 0, 0};
        if (av) af = *(const short8*)(hr + ks * 32);
#pragma unroll
        for (int ct = 0; ct < 3; ++ct)
            acc[ct] = __builtin_amdgcn_mfma_f32_16x16x32_bf16(af, bf[ct][ks], acc[ct], 0, 0, 0);
    }
    int orow = row0 + kh * 4;
    float dn[4];
#pragma unroll
    for (int i = 0; i < 4; ++i) dn[i] = (orow + i < N_NODES) ? dinv[orow + i] : 0.f;
#pragma unroll
    for (int ct = 0; ct < 3; ++ct) {
        int col = ct * 16 + bl;
#pragma unroll
        for (int i = 0; i < 4; ++i) {
            int r = orow + i;
            if (r < N_NODES) {
                u16 val = f2bf(acc[ct][i] * dn[i]);
                if (ct < 2)          hs2A[(size_t)r * 32 + col] = val;
                else if (bl < 8)     hs2B[(size_t)r * 8 + (col - 32)] = val;
            }
        }
    }
}

// ---------------- aggregation layer 1: 3 edges/wave-instr, u64 gathers ----
// 20 lanes/edge (16 hsA-u64 + 4 hsB-u64), groups at lanes 0-19/20-39/40-59.
// lane ll<16: feats 4ll..4ll+3 of hsA; ll 16..19: feats 64+4(ll-16).. of hsB.
__global__ __launch_bounds__(256) void aggregate1(
        const char* __restrict__ tab, int delta1,
        const int* __restrict__ rowStart, const int* __restrict__ csrSrc,
        const float* __restrict__ dinv, const float* __restrict__ bias,
        u32* __restrict__ out) {
    int wid = threadIdx.x >> 6, lane = threadIdx.x & 63;
    int node = __builtin_amdgcn_readfirstlane(blockIdx.x * 4 + wid);
    if (node >= N_NODES) return;
    int g = lane / 20;                 // pack group (3 = inactive)
    int ll = lane - 20 * g;
    bool isB = ll >= 16;
    u32 loff = isB ? (u32)(ll - 16) * 8 + (u32)delta1 : (u32)ll * 8;
    int sh = isB ? 5 : 7;
    bool act = lane < 60;
    const u32 hm = 0xFFFF0000u;
    float a0 = 0.f, a1 = 0.f, a2 = 0.f, a3 = 0.f;
    if (lane < 20) {                   // self-loop (group 0 only)
        u32x2 v = *(const u32x2*)(tab + (((u32)node << sh) + loff));
        a0 += uaf(v.x << 16); a1 += uaf(v.x & hm);
        a2 += uaf(v.y << 16); a3 += uaf(v.y & hm);
    }
    int j = rowStart[node], end = rowStart[node + 1];
    for (; j + 24 <= end; j += 24) {
        u32 iv[8]; u32x2 vv[8];
#pragma unroll
        for (int q = 0; q < 8; ++q) iv[q] = act ? (u32)csrSrc[j + 3 * q + g] : 0u;
#pragma unroll
        for (int q = 0; q < 8; ++q) {
            u32x2 z = {0u, 0u};
            vv[q] = act ? *(const u32x2*)(tab + ((iv[q] << sh) + loff)) : z;
        }
#pragma unroll
        for (int q = 0; q < 8; ++q) {
            a0 += uaf(vv[q].x << 16); a1 += uaf(vv[q].x & hm);
            a2 += uaf(vv[q].y << 16); a3 += uaf(vv[q].y & hm);
        }
    }
    for (; j < end; j += 3) {
        bool p = act && (j + g < end);
        u32 ivx = p ? (u32)csrSrc[j + g] : 0u;
        u32x2 z = {0u, 0u};
        u32x2 v = p ? *(const u32x2*)(tab + ((ivx << sh) + loff)) : z;
        a0 += uaf(v.x << 16); a1 += uaf(v.x & hm);
        a2 += uaf(v.y << 16); a3 += uaf(v.y & hm);
    }
    // fold groups 1,2 onto group 0
    a0 = a0 + __shfl(a0, lane + 20) + __shfl(a0, lane + 40);
    a1 = a1 + __shfl(a1, lane + 20) + __shfl(a1, lane + 40);
    a2 = a2 + __shfl(a2, lane + 20) + __shfl(a2, lane + 40);
    a3 = a3 + __shfl(a3, lane + 20) + __shfl(a3, lane + 40);
    if (lane < 20) {
        float dn = dinv[node];
        int f0 = 4 * ll;               // holds for hsA and hsB lanes
        float acc[4] = {a0, a1, a2, a3};
        float r[4];
#pragma unroll
        for (int k = 0; k < 4; ++k) {
            int f = f0 + k;
            float b = (f < HID) ? bias[f] : 0.f;
            r[k] = (f < HID) ? fmaxf(fmaf(dn, acc[k], b), 0.f) : 0.f;
        }
        u32x2 ov = { ((u32)f2bf(r[1]) << 16) | (u32)f2bf(r[0]),
                     ((u32)f2bf(r[3]) << 16) | (u32)f2bf(r[2]) };
        *(u32x2*)(out + (size_t)node * 48 + 2 * ll) = ov;   // cols 2ll,2ll+1
    }
}

// ---------------- aggregation layer 2: 6 edges/wave-instr + log_softmax ---
// 10 lanes/edge (8 hs2A-u64 + 2 hs2B-u64), groups at lanes 10g..10g+9.
__global__ __launch_bounds__(256) void aggregate2(
        const char* __restrict__ tab, int delta2,
        const int* __restrict__ rowStart, const int* __restrict__ csrSrc,
        const float* __restrict__ dinv, const float* __restrict__ bias,
        float* __restrict__ out) {
    int wid = threadIdx.x >> 6, lane = threadIdx.x & 63;
    int node = __builtin_amdgcn_readfirstlane(blockIdx.x * 4 + wid);
    if (node >= N_NODES) return;
    int g = lane / 10;                 // pack group 0..5 (6 = inactive)
    int ll = lane - 10 * g;
    bool isB = ll >= 8;
    u32 loff = isB ? (u32)(ll - 8) * 8 + (u32)delta2 : (u32)ll * 8;
    int sh = isB ? 4 : 6;
    bool act = lane < 60;
    const u32 hm = 0xFFFF0000u;
    float a0 = 0.f, a1 = 0.f, a2 = 0.f, a3 = 0.f;
    if (lane < 10) {                   // self-loop (group 0 only)
        u32x2 v = *(const u32x2*)(tab + (((u32)node << sh) + loff));
        a0 += uaf(v.x << 16); a1 += uaf(v.x & hm);
        a2 += uaf(v.y << 16); a3 += uaf(v.y & hm);
    }
    int j = rowStart[node], end = rowStart[node + 1];
    for (; j + 24 <= end; j += 24) {
        u32 iv[4]; u32x2 vv[4];
#pragma unroll
        for (int q = 0; q < 4; ++q) iv[q] = act ? (u32)csrSrc[j + 6 * q + g] : 0u;
#pragma unroll
        for (int q = 0; q < 4; ++q) {
            u32x2 z = {0u, 0u};
            vv[q] = act ? *(const u32x2*)(tab + ((iv[q] << sh) + loff)) : z;
        }
#pragma unroll
        for (int q = 0; q < 4; ++q) {
            a0 += uaf(vv[q].x << 16); a1 += uaf(vv[q].x & hm);
            a2 += uaf(vv[q].y << 16); a3 += uaf(vv[q].y & hm);
        }
    }
    for (; j < end; j += 6) {
        bool p = act && (j + g < end);
        u32 ivx = p ? (u32)csrSrc[j + g] : 0u;
        u32x2 z = {0u, 0u};
        u32x2 v = p ? *(const u32x2*)(tab + ((ivx << sh) + loff)) : z;
        a0 += uaf(v.x << 16); a1 += uaf(v.x & hm);
        a2 += uaf(v.y << 16); a3 += uaf(v.y & hm);
    }
    // fold 6 groups onto group 0: first +30, then +10,+20
    a0 = a0 + __shfl(a0, lane + 30);
    a1 = a1 + __shfl(a1, lane + 30);
    a2 = a2 + __shfl(a2, lane + 30);
    a3 = a3 + __shfl(a3, lane + 30);
    a0 = a0 + __shfl(a0, lane + 10) + __shfl(a0, lane + 20);
    a1 = a1 + __shfl(a1, lane + 10) + __shfl(a1, lane + 20);
    a2 = a2 + __shfl(a2, lane + 10) + __shfl(a2, lane + 20);
    a3 = a3 + __shfl(a3, lane + 10) + __shfl(a3, lane + 20);
    // softmax over 40 logits held as 4 regs x lanes 0..9 (xor-closed over 16)
    float v0 = 0.f, v1 = 0.f, v2 = 0.f, v3 = 0.f, m = -3.4e38f;
    if (lane < 10) {
        float dn = dinv[node];
        int f0 = 4 * ll;               // holds for hs2A and hs2B lanes
        v0 = fmaf(dn, a0, bias[f0 + 0]);
        v1 = fmaf(dn, a1, bias[f0 + 1]);
        v2 = fmaf(dn, a2, bias[f0 + 2]);
        v3 = fmaf(dn, a3, bias[f0 + 3]);
        m = fmaxf(fmaxf(v0, v1), fmaxf(v2, v3));
    }
#pragma unroll
    for (int o = 1; o < 16; o <<= 1) m = fmaxf(m, __shfl_xor(m, o));
    float e = (lane < 10)
        ? (expf(v0 - m) + expf(v1 - m) + expf(v2 - m) + expf(v3 - m)) : 0.f;
#pragma unroll
    for (int o = 1; o < 16; o <<= 1) e += __shfl_xor(e, o);
    float lse = logf(e);
    if (lane < 10) {
        float4 r = make_float4(v0 - m - lse, v1 - m - lse, v2 - m - lse, v3 - m - lse);
        *(float4*)(out + (size_t)node * OUT_CH + 4 * ll) = r;
    }
}

extern "C" void kernel_launch(void* const* d_in, const int* in_sizes, int n_in,
                              void* d_out, int out_size, void* d_ws, size_t ws_size,
                              hipStream_t stream) {
    const float* x  = (const float*)d_in[0];
    const int*   e  = (const int*)d_in[1];
    const float* W1 = (const float*)d_in[2];
    const float* b1 = (const float*)d_in[3];
    const float* W2 = (const float*)d_in[4];
    const float* b2 = (const float*)d_in[5];
    float* out = (float*)d_out;

    // workspace carve (all sizes multiples of 16 B); total ~59 MB
    char* w = (char*)d_ws;
    unsigned* bucketBuf = (unsigned*)w;                  // 15.68 MB, dead after passB
    u16* hsA = (u16*)w; w += (size_t)100032 * 64 * 2;    // 12.80 MB (aliases bucketBuf)
    u16* hsB = (u16*)w; w += (size_t)100032 * 16 * 2;    // 3.20 MB  (aliases bucketBuf)
    u16* h1b  = (u16*)w; w += (size_t)100032 * 96 * 2;   // 19.2 MB
    int* csrSrc = (int*)w; w += (size_t)N_EDGES * 4;     // 12.8 MB
    u16* hs2A = (u16*)w; w += (size_t)100032 * 32 * 2;   // 6.40 MB (offset 64B-aligned)
    u16* hs2B = (u16*)w; w += (size_t)100032 * 8 * 2;    // 1.60 MB
    int* rowStart = (int*)w; w += 400016;
    float* dinv   = (float*)w; w += 400000;
    int* bucketCursor = (int*)w; w += NB * 16 * 4;
    int* bucketStart  = (int*)w; w += 1024;
    u16* w1t = (u16*)w; w += 80 * 128 * 2;
    u16* w2t = (u16*)w; w += 48 * 96 * 2;
    int* flag = (int*)w; w += 16;

    int delta1 = (int)((char*)hsB - (char*)hsA);         // 12,804,096
    int delta2 = (int)((char*)hs2B - (char*)hs2A);       // 6,402,048

    probe64<<<1, 256, 0, stream>>>(e, flag);
    init_misc<<<3126, 256, 0, stream>>>(bucketCursor, (u32*)h1b);
    passA<<<(N_EDGES + PA_EDGES - 1) / PA_EDGES, 256, 0, stream>>>(
        e, flag, bucketCursor, bucketBuf);
    scan196<<<1, 256, 0, stream>>>(bucketCursor, bucketStart, rowStart);
    passB<<<NB, 1024, 0, stream>>>(bucketBuf, bucketCursor, bucketStart,
                                   csrSrc, rowStart, dinv);
    prep_w<<<16, 256, 0, stream>>>(W1, W2, w1t, w2t);

    gemm1_mfma<<<(N_NODES + 63) / 64, 256, 0, stream>>>(x, w1t, dinv, hsA, hsB);
    aggregate1<<<(N_NODES + 3) / 4, 256, 0, stream>>>(
        (const char*)hsA, delta1, rowStart, csrSrc, dinv, b1, (u32*)h1b);
    gemm2_mfma<<<(N_NODES + 63) / 64, 256, 0, stream>>>(h1b, w2t, dinv, hs2A, hs2B);
    aggregate2<<<(N_NODES + 3) / 4, 256, 0, stream>>>(
        (const char*)hs2A, delta2, rowStart, csrSrc, dinv, b2, out);
}

// Round 10
// 264.418 us; speedup vs baseline: 1.8636x; 1.0976x over previous
//
#include <hip/hip_runtime.h>

#define N_NODES 100000
#define IN_CH 128
#define HID 75
#define OUT_CH 40
#define N_EDGES 3200000

#define NB 196          // buckets of 512 dst nodes
#define CAP 20000       // per-bucket capacity; mean 16384
#define EPT 16          // edges per thread in passA
#define PA_EDGES (EPT * 256)

typedef unsigned short u16;
typedef unsigned int u32;
typedef unsigned char u8;
typedef short short8 __attribute__((ext_vector_type(8)));
typedef float f32x4 __attribute__((ext_vector_type(4)));
typedef float f32x2 __attribute__((ext_vector_type(2)));
typedef u32 u32x2 __attribute__((ext_vector_type(2)));
typedef u32 u32x4 __attribute__((ext_vector_type(4)));

__device__ __forceinline__ u16 f2bf(float f) {
    u32 b = __float_as_uint(f);
    b += 0x7FFF + ((b >> 16) & 1);   // round-to-nearest-even
    return (u16)(b >> 16);
}

#if __has_builtin(__builtin_amdgcn_cvt_pk_f32_fp8) && __has_builtin(__builtin_amdgcn_cvt_pk_fp8_f32)
#define HW_FP8 1
#else
#define HW_FP8 0
#endif

// ---- fp8 e4m3 decode: 2 values from the low/high word of a u32 -----------
__device__ __forceinline__ float dec1_sw(u32 v) {
    u32 s = (v & 0x80u) << 24;
    u32 em = v & 0x7Fu;
    float mag = (em >= 8u) ? __uint_as_float((em << 20) + (120u << 23))
                           : (float)em * 0.001953125f;   // denormal: m * 2^-9
    return __uint_as_float(s | __float_as_uint(mag));
}
template <int HI>
__device__ __forceinline__ f32x2 dec2(u32 w) {
#if HW_FP8
    return __builtin_amdgcn_cvt_pk_f32_fp8(w, HI);
#else
    f32x2 r;
    r.x = dec1_sw((w >> (HI * 16)) & 0xFFu);
    r.y = dec1_sw((w >> (HI * 16 + 8)) & 0xFFu);
    return r;
#endif
}
// ---- fp8 e4m3 encode (RNE, clamp to +-448) -------------------------------
__device__ __forceinline__ u32 enc1(float f) {
#if HW_FP8
    return __builtin_amdgcn_cvt_pk_fp8_f32(f, f, 0u, false) & 0xFFu;
#else
    float cf = fminf(fmaxf(f, -448.f), 448.f);
    u32 b = __float_as_uint(cf);
    u32 sign = (b >> 24) & 0x80u;
    float af = fabsf(cf);
    if (af < 0.015625f) {                       // denormal range, step 2^-9
        u32 d = (u32)__builtin_rintf(af * 512.f);
        return sign | d;                        // d==8 -> 0x08 = 2^-6 (valid)
    }
    u32 e = (b >> 23) & 0xFFu;
    u32 m = b & 0x7FFFFFu;
    u32 m8 = m >> 20;
    u32 rem = m & 0xFFFFFu;
    m8 += (rem > 0x80000u) || (rem == 0x80000u && (m8 & 1u));
    u32 ee = e - 120u;
    if (m8 == 8u) { m8 = 0u; ee += 1u; }
    if (ee > 15u || (ee == 15u && m8 == 7u)) { ee = 15u; m8 = 6u; }  // 448
    return sign | (ee << 3) | m8;
#endif
}

// ---------------- edge-index layout probe (int32 vs int64) ----------------
__global__ void probe64(const int* __restrict__ e, int* __restrict__ flag) {
    __shared__ int nonzero;
    if (threadIdx.x == 0) nonzero = 0;
    __syncthreads();
    int idx = threadIdx.x * 12497;              // < 3.2M
    if (e[2 * idx + 1] != 0) nonzero = 1;       // safe for both layouts
    __syncthreads();
    if (threadIdx.x == 0) *flag = (nonzero == 0) ? 1 : 0;
}

// zero bucket cursors + zero h1b K-pad (u32 cols 40..47; gemm2 reads them)
__global__ __launch_bounds__(256) void init_misc(int* __restrict__ bucketCursor,
        u32* __restrict__ h1b32) {
    int i = blockIdx.x * 256 + threadIdx.x;
    if (i < NB * 16) bucketCursor[i] = 0;
    if (i < 800000) {
        int node = i >> 3, q = i & 7;
        h1b32[node * 48 + 40 + q] = 0;
    }
}

// ---------------- pass A: bin edges into 196 dst-range buckets ------------
__global__ __launch_bounds__(256) void passA(const int* __restrict__ e,
        const int* __restrict__ flag, int* __restrict__ bucketCursor,
        unsigned* __restrict__ bucketBuf) {
    __shared__ int cnt[NB];
    __shared__ int base[NB];
    int t = threadIdx.x;
    for (int i = t; i < NB; i += 256) cnt[i] = 0;
    __syncthreads();
    bool w64 = (*flag != 0);
    int s_[EPT], d_[EPT];
    int eb = blockIdx.x * PA_EDGES + t;
#pragma unroll
    for (int k = 0; k < EPT; ++k) {
        int idx = eb + k * 256;
        int s = 0, d = -1;
        if (idx < N_EDGES) {
            if (w64) { s = e[2 * idx]; d = e[2 * (N_EDGES + idx)]; }
            else     { s = e[idx];     d = e[N_EDGES + idx]; }
            atomicAdd(&cnt[d >> 9], 1);
        }
        s_[k] = s; d_[k] = d;
    }
    __syncthreads();
    for (int i = t; i < NB; i += 256) {
        int c = cnt[i];
        base[i] = (c > 0) ? atomicAdd(&bucketCursor[i * 16], c) : 0;  // 64B-padded cursors
        cnt[i] = 0;
    }
    __syncthreads();
#pragma unroll
    for (int k = 0; k < EPT; ++k) {
        int d = d_[k];
        if (d >= 0) {
            int b = d >> 9;
            int off = atomicAdd(&cnt[b], 1);
            int pos = base[b] + off;
            if (pos < CAP)
                bucketBuf[(size_t)b * CAP + pos] =
                    ((unsigned)(d & 511) << 17) | (unsigned)s_[k];
        }
    }
}

// ---------------- scan of 196 bucket sizes -> bucket starts ---------------
__global__ __launch_bounds__(256) void scan196(const int* __restrict__ bucketCursor,
        int* __restrict__ bucketStart, int* __restrict__ rowStart) {
    __shared__ int a[256], b[256];
    int t = threadIdx.x;
    int v = (t < NB) ? bucketCursor[t * 16] : 0;
    a[t] = v;
    __syncthreads();
    int* pin = a; int* pout = b;
    for (int o = 1; o < 256; o <<= 1) {
        int nv = pin[t] + ((t >= o) ? pin[t - o] : 0);
        pout[t] = nv;
        __syncthreads();
        int* tmp = pin; pin = pout; pout = tmp;
    }
    if (t < NB) bucketStart[t] = pin[t] - v;  // exclusive
    if (t == 0) rowStart[N_NODES] = N_EDGES;
}

// ---------------- pass B: per-bucket CSR fill, all atomics in LDS ---------
__global__ __launch_bounds__(1024) void passB(const unsigned* __restrict__ bucketBuf,
        const int* __restrict__ bucketCursor, const int* __restrict__ bucketStart,
        int* __restrict__ csrSrc, int* __restrict__ rowStart, float* __restrict__ dinv) {
    __shared__ int cnt[512];
    __shared__ int sa[512], sb[512];
    int b = blockIdx.x;
    int t = threadIdx.x;
    int n = bucketCursor[b * 16];
    int start = bucketStart[b];
    if (t < 512) cnt[t] = 0;
    __syncthreads();
    const unsigned* buf = bucketBuf + (size_t)b * CAP;
    for (int i = t; i < n; i += 1024) atomicAdd(&cnt[buf[i] >> 17], 1);
    __syncthreads();
    if (t < 512) sa[t] = cnt[t];
    __syncthreads();
    int* pin = sa; int* pout = sb;
    for (int o = 1; o < 512; o <<= 1) {
        if (t < 512) pout[t] = pin[t] + ((t >= o) ? pin[t - o] : 0);
        __syncthreads();
        int* tmp = pin; pin = pout; pout = tmp;
    }
    int excl = 0;
    if (t < 512) {
        int deg = cnt[t];
        excl = pin[t] - deg;
        int node = b * 512 + t;
        if (node < N_NODES) {
            rowStart[node] = start + excl;
            dinv[node] = rsqrtf((float)deg + 1.0f);  // +1 self-loop
        }
    }
    __syncthreads();
    if (t < 512) cnt[t] = excl;   // LDS cursors
    __syncthreads();
    for (int i = t; i < n; i += 1024) {
        unsigned p = buf[i];
        int pos = atomicAdd(&cnt[p >> 17], 1);
        csrSrc[start + pos] = (int)(p & 0x1FFFF);
    }
}

// ---------------- prep: bf16 transposed weights ---------------------------
__global__ __launch_bounds__(256) void prep_w(const float* __restrict__ W1,
        const float* __restrict__ W2, u16* __restrict__ w1t, u16* __restrict__ w2t) {
    int g = blockIdx.x * 256 + threadIdx.x;
    int stride = gridDim.x * 256;
    for (int i = g; i < 80 * 128; i += stride) {
        int c = i >> 7, k = i & 127;
        w1t[i] = (c < HID) ? f2bf(W1[k * HID + c]) : (u16)0;
    }
    for (int i = g; i < 48 * 96; i += stride) {
        int c = i / 96, k = i - c * 96;
        w2t[i] = (c < OUT_CH && k < HID) ? f2bf(W2[k * OUT_CH + c]) : (u16)0;
    }
}

// ---------------- GEMM1 via MFMA -> fp8 tables (SCALE=8 folded in) --------
// hsA8[node][64 u8] (feats 0..63, 64B rows), hsB8[node][16 u8] (feats 64..79)
__global__ __launch_bounds__(256) void gemm1_mfma(const float* __restrict__ x,
        const u16* __restrict__ w1t, const float* __restrict__ dinv,
        u8* __restrict__ hsA8, u8* __restrict__ hsB8) {
    __shared__ u16 Wl[80 * 136];   // pad 128->136 elems: bank-spread rows
    int t = threadIdx.x;
    {
        const u32* ws = (const u32*)w1t;
        u32* wd = (u32*)Wl;
        for (int i = t; i < 80 * 64; i += 256) {
            int r = i >> 6, c = i & 63;
            wd[r * 68 + c] = ws[i];
        }
    }
    __syncthreads();
    int wid = t >> 6, lane = t & 63;
    int bl = lane & 15, kh = lane >> 4;
    int row0 = blockIdx.x * 64 + wid * 16;
    short8 bf[5][4];
#pragma unroll
    for (int ct = 0; ct < 5; ++ct)
#pragma unroll
        for (int ks = 0; ks < 4; ++ks)
            bf[ct][ks] = *(const short8*)&Wl[(ct * 16 + bl) * 136 + ks * 32 + kh * 8];
    f32x4 zero = {0.f, 0.f, 0.f, 0.f};
    f32x4 acc[5];
#pragma unroll
    for (int ct = 0; ct < 5; ++ct) acc[ct] = zero;
    int arow = row0 + bl;
    bool av = (arow < N_NODES);
    const float* xr = x + (size_t)arow * IN_CH + kh * 8;
#pragma unroll
    for (int ks = 0; ks < 4; ++ks) {
        short8 af = {0, 0, 0, 0, 0, 0, 0, 0};
        if (av) {
            float4 lo = *(const float4*)(xr + ks * 32);
            float4 hi = *(const float4*)(xr + ks * 32 + 4);
            af[0] = (short)f2bf(lo.x); af[1] = (short)f2bf(lo.y);
            af[2] = (short)f2bf(lo.z); af[3] = (short)f2bf(lo.w);
            af[4] = (short)f2bf(hi.x); af[5] = (short)f2bf(hi.y);
            af[6] = (short)f2bf(hi.z); af[7] = (short)f2bf(hi.w);
        }
#pragma unroll
        for (int ct = 0; ct < 5; ++ct)
            acc[ct] = __builtin_amdgcn_mfma_f32_16x16x32_bf16(af, bf[ct][ks], acc[ct], 0, 0, 0);
    }
    // C/D: col = lane&15, row = (lane>>4)*4 + reg  [HW-verified]
    int orow = row0 + kh * 4;
    float dn[4];
#pragma unroll
    for (int i = 0; i < 4; ++i)
        dn[i] = (orow + i < N_NODES) ? dinv[orow + i] * 8.f : 0.f;   // SCALE=8
#pragma unroll
    for (int ct = 0; ct < 5; ++ct) {
        int col = ct * 16 + bl;
#pragma unroll
        for (int i = 0; i < 4; ++i) {
            int r = orow + i;
            if (r < N_NODES) {
                u8 q8 = (u8)enc1(acc[ct][i] * dn[i]);
                if (ct < 4) hsA8[(size_t)r * 64 + col] = q8;
                else        hsB8[(size_t)r * 16 + (col - 64)] = q8;
            }
        }
    }
}

// ---------------- GEMM2 via MFMA -> fp8 tables (SCALE=8) ------------------
// hs2A8[node][32 u8] (feats 0..31), hs2B8[node][8 u8] (feats 32..39)
__global__ __launch_bounds__(256) void gemm2_mfma(const u16* __restrict__ h1b,
        const u16* __restrict__ w2t, const float* __restrict__ dinv,
        u8* __restrict__ hs2A8, u8* __restrict__ hs2B8) {
    __shared__ u16 Wl[48 * 104];   // pad 96->104
    int t = threadIdx.x;
    {
        const u32* ws = (const u32*)w2t;
        u32* wd = (u32*)Wl;
        for (int i = t; i < 48 * 48; i += 256) {
            int r = i / 48, c = i - r * 48;
            wd[r * 52 + c] = ws[i];
        }
    }
    __syncthreads();
    int wid = t >> 6, lane = t & 63;
    int bl = lane & 15, kh = lane >> 4;
    int row0 = blockIdx.x * 64 + wid * 16;
    short8 bf[3][3];
#pragma unroll
    for (int ct = 0; ct < 3; ++ct)
#pragma unroll
        for (int ks = 0; ks < 3; ++ks)
            bf[ct][ks] = *(const short8*)&Wl[(ct * 16 + bl) * 104 + ks * 32 + kh * 8];
    f32x4 zero = {0.f, 0.f, 0.f, 0.f};
    f32x4 acc[3];
#pragma unroll
    for (int ct = 0; ct < 3; ++ct) acc[ct] = zero;
    int arow = row0 + bl;
    bool av = (arow < N_NODES);
    const u16* hr = h1b + (size_t)arow * 96 + kh * 8;
#pragma unroll
    for (int ks = 0; ks < 3; ++ks) {
        short8 af = {0, 0, 0, 0, 0, 0, 0, 0};
        if (av) af = *(const short8*)(hr + ks * 32);
#pragma unroll
        for (int ct = 0; ct < 3; ++ct)
            acc[ct] = __builtin_amdgcn_mfma_f32_16x16x32_bf16(af, bf[ct][ks], acc[ct], 0, 0, 0);
    }
    int orow = row0 + kh * 4;
    float dn[4];
#pragma unroll
    for (int i = 0; i < 4; ++i)
        dn[i] = (orow + i < N_NODES) ? dinv[orow + i] * 8.f : 0.f;   // SCALE=8
#pragma unroll
    for (int ct = 0; ct < 3; ++ct) {
        int col = ct * 16 + bl;
#pragma unroll
        for (int i = 0; i < 4; ++i) {
            int r = orow + i;
            if (r < N_NODES) {
                u8 q8 = (u8)enc1(acc[ct][i] * dn[i]);
                if (ct < 2)      hs2A8[(size_t)r * 32 + col] = q8;
                else if (bl < 8) hs2B8[(size_t)r * 8 + (col - 32)] = q8;
            }
        }
    }
}

// ---------------- aggregation layer 1: fp8, 6 edges/wave-instr ------------
// 10 lanes/edge (8 x u64 of hsA8 + 2 x u64 of hsB8); lane ll holds feats
// 8ll..8ll+7. Fold 6 groups, epilogue lanes 0..9 write bf16 h1b (u32x4).
__global__ __launch_bounds__(256) void aggregate1(
        const char* __restrict__ tab, int delta1,
        const int* __restrict__ rowStart, const int* __restrict__ csrSrc,
        const float* __restrict__ dinv, const float* __restrict__ bias,
        u32* __restrict__ out) {
    int wid = threadIdx.x >> 6, lane = threadIdx.x & 63;
    int node = __builtin_amdgcn_readfirstlane(blockIdx.x * 4 + wid);
    if (node >= N_NODES) return;
    int g = lane / 10;                 // pack group (6 = inactive)
    int ll = lane - 10 * g;
    bool isB = ll >= 8;
    u32 loff = isB ? (u32)(ll - 8) * 8 + (u32)delta1 : (u32)ll * 8;
    int sh = isB ? 4 : 6;              // row stride 16B / 64B
    bool act = lane < 60;
    f32x2 a0 = {0.f, 0.f}, a1 = {0.f, 0.f}, a2 = {0.f, 0.f}, a3 = {0.f, 0.f};
    if (lane < 10) {                   // self-loop (group 0 only)
        u32x2 v = *(const u32x2*)(tab + (((u32)node << sh) + loff));
        a0 += dec2<0>(v.x); a1 += dec2<1>(v.x);
        a2 += dec2<0>(v.y); a3 += dec2<1>(v.y);
    }
    int j = rowStart[node], end = rowStart[node + 1];
    for (; j + 24 <= end; j += 24) {
        u32 iv[4]; u32x2 vv[4];
#pragma unroll
        for (int q = 0; q < 4; ++q) iv[q] = act ? (u32)csrSrc[j + 6 * q + g] : 0u;
#pragma unroll
        for (int q = 0; q < 4; ++q) {
            u32x2 z = {0u, 0u};
            vv[q] = act ? *(const u32x2*)(tab + ((iv[q] << sh) + loff)) : z;
        }
#pragma unroll
        for (int q = 0; q < 4; ++q) {
            a0 += dec2<0>(vv[q].x); a1 += dec2<1>(vv[q].x);
            a2 += dec2<0>(vv[q].y); a3 += dec2<1>(vv[q].y);
        }
    }
    for (; j < end; j += 6) {
        bool p = act && (j + g < end);
        u32 ivx = p ? (u32)csrSrc[j + g] : 0u;
        u32x2 z = {0u, 0u};
        u32x2 v = p ? *(const u32x2*)(tab + ((ivx << sh) + loff)) : z;
        a0 += dec2<0>(v.x); a1 += dec2<1>(v.x);
        a2 += dec2<0>(v.y); a3 += dec2<1>(v.y);
    }
    float tt[8] = {a0.x, a0.y, a1.x, a1.y, a2.x, a2.y, a3.x, a3.y};
#pragma unroll
    for (int k = 0; k < 8; ++k) {      // fold groups {0,3},{1,4},{2,5} -> 0
        tt[k] += __shfl(tt[k], lane + 30);
        tt[k] += __shfl(tt[k], lane + 10) + __shfl(tt[k], lane + 20);
    }
    if (lane < 10) {
        float dns = dinv[node] * 0.125f;   // undo SCALE=8
        u32x4 ov;
#pragma unroll
        for (int k = 0; k < 4; ++k) {
            int f0 = 8 * ll + 2 * k;
            float rlo = (f0 < HID) ? fmaxf(fmaf(dns, tt[2 * k], bias[f0]), 0.f) : 0.f;
            float rhi = (f0 + 1 < HID) ? fmaxf(fmaf(dns, tt[2 * k + 1], bias[f0 + 1]), 0.f) : 0.f;
            ov[k] = ((u32)f2bf(rhi) << 16) | (u32)f2bf(rlo);
        }
        *(u32x4*)(out + (size_t)node * 48 + 4 * ll) = ov;
    }
}

// ---------------- aggregation layer 2: fp8, 12 edges/wave + log_softmax ---
// 5 lanes/edge (4 x u64 hs2A8 + 1 x u64 hs2B8); lane ll holds feats 8ll..8ll+7.
__global__ __launch_bounds__(256) void aggregate2(
        const char* __restrict__ tab, int delta2,
        const int* __restrict__ rowStart, const int* __restrict__ csrSrc,
        const float* __restrict__ dinv, const float* __restrict__ bias,
        float* __restrict__ out) {
    int wid = threadIdx.x >> 6, lane = threadIdx.x & 63;
    int node = __builtin_amdgcn_readfirstlane(blockIdx.x * 4 + wid);
    if (node >= N_NODES) return;
    int g = lane / 5;                  // pack group 0..11 (12 = inactive)
    int ll = lane - 5 * g;
    bool isB = (ll == 4);
    u32 loff = isB ? (u32)delta2 : (u32)ll * 8;
    int sh = isB ? 3 : 5;              // row stride 8B / 32B
    bool act = lane < 60;
    f32x2 a0 = {0.f, 0.f}, a1 = {0.f, 0.f}, a2 = {0.f, 0.f}, a3 = {0.f, 0.f};
    if (lane < 5) {                    // self-loop (group 0 only)
        u32x2 v = *(const u32x2*)(tab + (((u32)node << sh) + loff));
        a0 += dec2<0>(v.x); a1 += dec2<1>(v.x);
        a2 += dec2<0>(v.y); a3 += dec2<1>(v.y);
    }
    int j = rowStart[node], end = rowStart[node + 1];
    for (; j + 24 <= end; j += 24) {
        u32 iv[2]; u32x2 vv[2];
#pragma unroll
        for (int q = 0; q < 2; ++q) iv[q] = act ? (u32)csrSrc[j + 12 * q + g] : 0u;
#pragma unroll
        for (int q = 0; q < 2; ++q) {
            u32x2 z = {0u, 0u};
            vv[q] = act ? *(const u32x2*)(tab + ((iv[q] << sh) + loff)) : z;
        }
#pragma unroll
        for (int q = 0; q < 2; ++q) {
            a0 += dec2<0>(vv[q].x); a1 += dec2<1>(vv[q].x);
            a2 += dec2<0>(vv[q].y); a3 += dec2<1>(vv[q].y);
        }
    }
    for (; j < end; j += 12) {
        bool p = act && (j + g < end);
        u32 ivx = p ? (u32)csrSrc[j + g] : 0u;
        u32x2 z = {0u, 0u};
        u32x2 v = p ? *(const u32x2*)(tab + ((ivx << sh) + loff)) : z;
        a0 += dec2<0>(v.x); a1 += dec2<1>(v.x);
        a2 += dec2<0>(v.y); a3 += dec2<1>(v.y);
    }
    float tt[8] = {a0.x, a0.y, a1.x, a1.y, a2.x, a2.y, a3.x, a3.y};
#pragma unroll
    for (int k = 0; k < 8; ++k) {      // fold 12 groups of 5 lanes -> group 0
        tt[k] += __shfl(tt[k], lane + 30);                       // g += g+6
        tt[k] += __shfl(tt[k], lane + 10) + __shfl(tt[k], lane + 20); // += g+2,g+4
        tt[k] += __shfl(tt[k], lane + 5);                        // g0 += g1
    }
    // softmax over 40 logits: lanes 0..4 hold 8 each (xor-closed over 8 lanes)
    bool act5 = lane < 5;
    float vk[8];
    float m = -3.4e38f;
    if (act5) {
        float dns = dinv[node] * 0.125f;   // undo SCALE=8
#pragma unroll
        for (int k = 0; k < 8; ++k) {
            vk[k] = fmaf(dns, tt[k], bias[8 * ll + k]);
            m = fmaxf(m, vk[k]);
        }
    }
#pragma unroll
    for (int o = 1; o < 8; o <<= 1) m = fmaxf(m, __shfl_xor(m, o));
    float e = 0.f;
    if (act5) {
#pragma unroll
        for (int k = 0; k < 8; ++k) e += expf(vk[k] - m);
    }
#pragma unroll
    for (int o = 1; o < 8; o <<= 1) e += __shfl_xor(e, o);
    float lse = logf(e);
    if (act5) {
        float4 r0 = make_float4(vk[0] - m - lse, vk[1] - m - lse,
                                vk[2] - m - lse, vk[3] - m - lse);
        float4 r1 = make_float4(vk[4] - m - lse, vk[5] - m - lse,
                                vk[6] - m - lse, vk[7] - m - lse);
        *(float4*)(out + (size_t)node * OUT_CH + 8 * ll) = r0;
        *(float4*)(out + (size_t)node * OUT_CH + 8 * ll + 4) = r1;
    }
}

extern "C" void kernel_launch(void* const* d_in, const int* in_sizes, int n_in,
                              void* d_out, int out_size, void* d_ws, size_t ws_size,
                              hipStream_t stream) {
    const float* x  = (const float*)d_in[0];
    const int*   e  = (const int*)d_in[1];
    const float* W1 = (const float*)d_in[2];
    const float* b1 = (const float*)d_in[3];
    const float* W2 = (const float*)d_in[4];
    const float* b2 = (const float*)d_in[5];
    float* out = (float*)d_out;

    // workspace carve (all sizes multiples of 16 B); total ~53 MB
    char* w = (char*)d_ws;
    u8* hsA8 = (u8*)w;                                   // 6.40 MB  (aliases bucketBuf)
    u8* hsB8 = (u8*)(w + 6402048);                       // 1.60 MB  (aliases bucketBuf)
    unsigned* bucketBuf = (unsigned*)w;                  // 15.68 MB, dead after passB
    w += 15680000;
    u16* h1b  = (u16*)w; w += (size_t)100032 * 96 * 2;   // 19.2 MB
    int* csrSrc = (int*)w; w += (size_t)N_EDGES * 4;     // 12.8 MB
    u8* hs2A8 = (u8*)w; w += (size_t)100032 * 32;        // 3.20 MB
    u8* hs2B8 = (u8*)w; w += (size_t)100032 * 8;         // 0.80 MB
    int* rowStart = (int*)w; w += 400016;
    float* dinv   = (float*)w; w += 400000;
    int* bucketCursor = (int*)w; w += NB * 16 * 4;
    int* bucketStart  = (int*)w; w += 1024;
    u16* w1t = (u16*)w; w += 80 * 128 * 2;
    u16* w2t = (u16*)w; w += 48 * 96 * 2;
    int* flag = (int*)w; w += 16;

    int delta1 = (int)((char*)hsB8 - (char*)hsA8);       // 6,402,048
    int delta2 = (int)((char*)hs2B8 - (char*)hs2A8);     // 3,201,024

    probe64<<<1, 256, 0, stream>>>(e, flag);
    init_misc<<<3126, 256, 0, stream>>>(bucketCursor, (u32*)h1b);
    passA<<<(N_EDGES + PA_EDGES - 1) / PA_EDGES, 256, 0, stream>>>(
        e, flag, bucketCursor, bucketBuf);
    scan196<<<1, 256, 0, stream>>>(bucketCursor, bucketStart, rowStart);
    passB<<<NB, 1024, 0, stream>>>(bucketBuf, bucketCursor, bucketStart,
                                   csrSrc, rowStart, dinv);
    prep_w<<<16, 256, 0, stream>>>(W1, W2, w1t, w2t);

    gemm1_mfma<<<(N_NODES + 63) / 64, 256, 0, stream>>>(x, w1t, dinv, hsA8, hsB8);
    aggregate1<<<(N_NODES + 3) / 4, 256, 0, stream>>>(
        (const char*)hsA8, delta1, rowStart, csrSrc, dinv, b1, (u32*)h1b);
    gemm2_mfma<<<(N_NODES + 63) / 64, 256, 0, stream>>>(h1b, w2t, dinv, hs2A8, hs2B8);
    aggregate2<<<(N_NODES + 3) / 4, 256, 0, stream>>>(
        (const char*)hs2A8, delta2, rowStart, csrSrc, dinv, b2, out);
}

// Round 11
// 257.584 us; speedup vs baseline: 1.9131x; 1.0265x over previous
//
#include <hip/hip_runtime.h>

#define N_NODES 100000
#define IN_CH 128
#define HID 75
#define OUT_CH 40
#define N_EDGES 3200000

#define NB 196          // buckets of 512 dst nodes
#define CAP 20000       // per-bucket capacity; mean 16384
#define EPT 16          // edges per thread in passA
#define PA_EDGES (EPT * 256)

typedef unsigned short u16;
typedef unsigned int u32;
typedef unsigned char u8;
typedef short short8 __attribute__((ext_vector_type(8)));
typedef float f32x4 __attribute__((ext_vector_type(4)));
typedef float f32x2 __attribute__((ext_vector_type(2)));
typedef u32 u32x2 __attribute__((ext_vector_type(2)));
typedef u32 u32x4 __attribute__((ext_vector_type(4)));

__device__ __forceinline__ u16 f2bf(float f) {
    u32 b = __float_as_uint(f);
    b += 0x7FFF + ((b >> 16) & 1);   // round-to-nearest-even
    return (u16)(b >> 16);
}

#if __has_builtin(__builtin_amdgcn_cvt_pk_f32_fp8) && __has_builtin(__builtin_amdgcn_cvt_pk_fp8_f32)
#define HW_FP8 1
#else
#define HW_FP8 0
#endif

// ---- fp8 e4m3 decode: 2 values from the low/high word of a u32 -----------
__device__ __forceinline__ float dec1_sw(u32 v) {
    u32 s = (v & 0x80u) << 24;
    u32 em = v & 0x7Fu;
    float mag = (em >= 8u) ? __uint_as_float((em << 20) + (120u << 23))
                           : (float)em * 0.001953125f;   // denormal: m * 2^-9
    return __uint_as_float(s | __float_as_uint(mag));
}
template <int HI>
__device__ __forceinline__ f32x2 dec2(u32 w) {
#if HW_FP8
    return __builtin_amdgcn_cvt_pk_f32_fp8(w, HI);
#else
    f32x2 r;
    r.x = dec1_sw((w >> (HI * 16)) & 0xFFu);
    r.y = dec1_sw((w >> (HI * 16 + 8)) & 0xFFu);
    return r;
#endif
}
// ---- fp8 e4m3 encode (RNE, clamp to +-448) -------------------------------
__device__ __forceinline__ u32 enc1(float f) {
#if HW_FP8
    return __builtin_amdgcn_cvt_pk_fp8_f32(f, f, 0u, false) & 0xFFu;
#else
    float cf = fminf(fmaxf(f, -448.f), 448.f);
    u32 b = __float_as_uint(cf);
    u32 sign = (b >> 24) & 0x80u;
    float af = fabsf(cf);
    if (af < 0.015625f) {                       // denormal range, step 2^-9
        u32 d = (u32)__builtin_rintf(af * 512.f);
        return sign | d;
    }
    u32 e = (b >> 23) & 0xFFu;
    u32 m = b & 0x7FFFFFu;
    u32 m8 = m >> 20;
    u32 rem = m & 0xFFFFFu;
    m8 += (rem > 0x80000u) || (rem == 0x80000u && (m8 & 1u));
    u32 ee = e - 120u;
    if (m8 == 8u) { m8 = 0u; ee += 1u; }
    if (ee > 15u || (ee == 15u && m8 == 7u)) { ee = 15u; m8 = 6u; }  // 448
    return sign | (ee << 3) | m8;
#endif
}

// ---------------- edge-index layout probe (int32 vs int64) ----------------
__global__ void probe64(const int* __restrict__ e, int* __restrict__ flag) {
    __shared__ int nonzero;
    if (threadIdx.x == 0) nonzero = 0;
    __syncthreads();
    int idx = threadIdx.x * 12497;              // < 3.2M
    if (e[2 * idx + 1] != 0) nonzero = 1;       // safe for both layouts
    __syncthreads();
    if (threadIdx.x == 0) *flag = (nonzero == 0) ? 1 : 0;
}

// zero bucket cursors + zero h1b K-pad (u32 cols 40..47; gemm2 reads them)
__global__ __launch_bounds__(256) void init_misc(int* __restrict__ bucketCursor,
        u32* __restrict__ h1b32) {
    int i = blockIdx.x * 256 + threadIdx.x;
    if (i < NB * 16) bucketCursor[i] = 0;
    if (i < 800000) {
        int node = i >> 3, q = i & 7;
        h1b32[node * 48 + 40 + q] = 0;
    }
}

// ---------------- pass A: bin edges into 196 dst-range buckets ------------
__global__ __launch_bounds__(256) void passA(const int* __restrict__ e,
        const int* __restrict__ flag, int* __restrict__ bucketCursor,
        unsigned* __restrict__ bucketBuf) {
    __shared__ int cnt[NB];
    __shared__ int base[NB];
    int t = threadIdx.x;
    for (int i = t; i < NB; i += 256) cnt[i] = 0;
    __syncthreads();
    bool w64 = (*flag != 0);
    int s_[EPT], d_[EPT];
    int eb = blockIdx.x * PA_EDGES + t;
#pragma unroll
    for (int k = 0; k < EPT; ++k) {
        int idx = eb + k * 256;
        int s = 0, d = -1;
        if (idx < N_EDGES) {
            if (w64) { s = e[2 * idx]; d = e[2 * (N_EDGES + idx)]; }
            else     { s = e[idx];     d = e[N_EDGES + idx]; }
            atomicAdd(&cnt[d >> 9], 1);
        }
        s_[k] = s; d_[k] = d;
    }
    __syncthreads();
    for (int i = t; i < NB; i += 256) {
        int c = cnt[i];
        base[i] = (c > 0) ? atomicAdd(&bucketCursor[i * 16], c) : 0;  // 64B-padded cursors
        cnt[i] = 0;
    }
    __syncthreads();
#pragma unroll
    for (int k = 0; k < EPT; ++k) {
        int d = d_[k];
        if (d >= 0) {
            int b = d >> 9;
            int off = atomicAdd(&cnt[b], 1);
            int pos = base[b] + off;
            if (pos < CAP)
                bucketBuf[(size_t)b * CAP + pos] =
                    ((unsigned)(d & 511) << 17) | (unsigned)s_[k];
        }
    }
}

// ---------------- scan of 196 bucket sizes -> bucket starts ---------------
__global__ __launch_bounds__(256) void scan196(const int* __restrict__ bucketCursor,
        int* __restrict__ bucketStart, int* __restrict__ rowStart) {
    __shared__ int a[256], b[256];
    int t = threadIdx.x;
    int v = (t < NB) ? bucketCursor[t * 16] : 0;
    a[t] = v;
    __syncthreads();
    int* pin = a; int* pout = b;
    for (int o = 1; o < 256; o <<= 1) {
        int nv = pin[t] + ((t >= o) ? pin[t - o] : 0);
        pout[t] = nv;
        __syncthreads();
        int* tmp = pin; pin = pout; pout = tmp;
    }
    if (t < NB) bucketStart[t] = pin[t] - v;  // exclusive
    if (t == 0) rowStart[N_NODES] = N_EDGES;
}

// ---------------- pass B: per-bucket CSR fill, all atomics in LDS ---------
__global__ __launch_bounds__(1024) void passB(const unsigned* __restrict__ bucketBuf,
        const int* __restrict__ bucketCursor, const int* __restrict__ bucketStart,
        int* __restrict__ csrSrc, int* __restrict__ rowStart, float* __restrict__ dinv) {
    __shared__ int cnt[512];
    __shared__ int sa[512], sb[512];
    int b = blockIdx.x;
    int t = threadIdx.x;
    int n = bucketCursor[b * 16];
    int start = bucketStart[b];
    if (t < 512) cnt[t] = 0;
    __syncthreads();
    const unsigned* buf = bucketBuf + (size_t)b * CAP;
    for (int i = t; i < n; i += 1024) atomicAdd(&cnt[buf[i] >> 17], 1);
    __syncthreads();
    if (t < 512) sa[t] = cnt[t];
    __syncthreads();
    int* pin = sa; int* pout = sb;
    for (int o = 1; o < 512; o <<= 1) {
        if (t < 512) pout[t] = pin[t] + ((t >= o) ? pin[t - o] : 0);
        __syncthreads();
        int* tmp = pin; pin = pout; pout = tmp;
    }
    int excl = 0;
    if (t < 512) {
        int deg = cnt[t];
        excl = pin[t] - deg;
        int node = b * 512 + t;
        if (node < N_NODES) {
            rowStart[node] = start + excl;
            dinv[node] = rsqrtf((float)deg + 1.0f);  // +1 self-loop
        }
    }
    __syncthreads();
    if (t < 512) cnt[t] = excl;   // LDS cursors
    __syncthreads();
    for (int i = t; i < n; i += 1024) {
        unsigned p = buf[i];
        int pos = atomicAdd(&cnt[p >> 17], 1);
        csrSrc[start + pos] = (int)(p & 0x1FFFF);
    }
}

// ---------------- prep: bf16 transposed weights ---------------------------
__global__ __launch_bounds__(256) void prep_w(const float* __restrict__ W1,
        const float* __restrict__ W2, u16* __restrict__ w1t, u16* __restrict__ w2t) {
    int g = blockIdx.x * 256 + threadIdx.x;
    int stride = gridDim.x * 256;
    for (int i = g; i < 80 * 128; i += stride) {
        int c = i >> 7, k = i & 127;
        w1t[i] = (c < HID) ? f2bf(W1[k * HID + c]) : (u16)0;
    }
    for (int i = g; i < 48 * 96; i += stride) {
        int c = i / 96, k = i - c * 96;
        w2t[i] = (c < OUT_CH && k < HID) ? f2bf(W2[k * OUT_CH + c]) : (u16)0;
    }
}

// ---------------- GEMM1 via MFMA -> fp8 tables (SCALE=8 folded in) --------
// hsA8[node][64 u8] (feats 0..63, 64B rows), hsB8[node][16 u8] (feats 64..79)
__global__ __launch_bounds__(256) void gemm1_mfma(const float* __restrict__ x,
        const u16* __restrict__ w1t, const float* __restrict__ dinv,
        u8* __restrict__ hsA8, u8* __restrict__ hsB8) {
    __shared__ u16 Wl[80 * 136];   // pad 128->136 elems: bank-spread rows
    int t = threadIdx.x;
    {
        const u32* ws = (const u32*)w1t;
        u32* wd = (u32*)Wl;
        for (int i = t; i < 80 * 64; i += 256) {
            int r = i >> 6, c = i & 63;
            wd[r * 68 + c] = ws[i];
        }
    }
    __syncthreads();
    int wid = t >> 6, lane = t & 63;
    int bl = lane & 15, kh = lane >> 4;
    int row0 = blockIdx.x * 64 + wid * 16;
    short8 bf[5][4];
#pragma unroll
    for (int ct = 0; ct < 5; ++ct)
#pragma unroll
        for (int ks = 0; ks < 4; ++ks)
            bf[ct][ks] = *(const short8*)&Wl[(ct * 16 + bl) * 136 + ks * 32 + kh * 8];
    f32x4 zero = {0.f, 0.f, 0.f, 0.f};
    f32x4 acc[5];
#pragma unroll
    for (int ct = 0; ct < 5; ++ct) acc[ct] = zero;
    int arow = row0 + bl;
    bool av = (arow < N_NODES);
    const float* xr = x + (size_t)arow * IN_CH + kh * 8;
#pragma unroll
    for (int ks = 0; ks < 4; ++ks) {
        short8 af = {0, 0, 0, 0, 0, 0, 0, 0};
        if (av) {
            float4 lo = *(const float4*)(xr + ks * 32);
            float4 hi = *(const float4*)(xr + ks * 32 + 4);
            af[0] = (short)f2bf(lo.x); af[1] = (short)f2bf(lo.y);
            af[2] = (short)f2bf(lo.z); af[3] = (short)f2bf(lo.w);
            af[4] = (short)f2bf(hi.x); af[5] = (short)f2bf(hi.y);
            af[6] = (short)f2bf(hi.z); af[7] = (short)f2bf(hi.w);
        }
#pragma unroll
        for (int ct = 0; ct < 5; ++ct)
            acc[ct] = __builtin_amdgcn_mfma_f32_16x16x32_bf16(af, bf[ct][ks], acc[ct], 0, 0, 0);
    }
    // C/D: col = lane&15, row = (lane>>4)*4 + reg  [HW-verified]
    int orow = row0 + kh * 4;
    float dn[4];
#pragma unroll
    for (int i = 0; i < 4; ++i)
        dn[i] = (orow + i < N_NODES) ? dinv[orow + i] * 8.f : 0.f;   // SCALE=8
#pragma unroll
    for (int ct = 0; ct < 5; ++ct) {
        int col = ct * 16 + bl;
#pragma unroll
        for (int i = 0; i < 4; ++i) {
            int r = orow + i;
            if (r < N_NODES) {
                u8 q8 = (u8)enc1(acc[ct][i] * dn[i]);
                if (ct < 4) hsA8[(size_t)r * 64 + col] = q8;
                else        hsB8[(size_t)r * 16 + (col - 64)] = q8;
            }
        }
    }
}

// ---------------- GEMM2 via MFMA -> single padded fp8 table (SCALE=8) -----
// hs2P[node][64 u8]: feats 0..39 in bytes 0..39, bytes 40..63 unused pad
__global__ __launch_bounds__(256) void gemm2_mfma(const u16* __restrict__ h1b,
        const u16* __restrict__ w2t, const float* __restrict__ dinv,
        u8* __restrict__ hs2P) {
    __shared__ u16 Wl[48 * 104];   // pad 96->104
    int t = threadIdx.x;
    {
        const u32* ws = (const u32*)w2t;
        u32* wd = (u32*)Wl;
        for (int i = t; i < 48 * 48; i += 256) {
            int r = i / 48, c = i - r * 48;
            wd[r * 52 + c] = ws[i];
        }
    }
    __syncthreads();
    int wid = t >> 6, lane = t & 63;
    int bl = lane & 15, kh = lane >> 4;
    int row0 = blockIdx.x * 64 + wid * 16;
    short8 bf[3][3];
#pragma unroll
    for (int ct = 0; ct < 3; ++ct)
#pragma unroll
        for (int ks = 0; ks < 3; ++ks)
            bf[ct][ks] = *(const short8*)&Wl[(ct * 16 + bl) * 104 + ks * 32 + kh * 8];
    f32x4 zero = {0.f, 0.f, 0.f, 0.f};
    f32x4 acc[3];
#pragma unroll
    for (int ct = 0; ct < 3; ++ct) acc[ct] = zero;
    int arow = row0 + bl;
    bool av = (arow < N_NODES);
    const u16* hr = h1b + (size_t)arow * 96 + kh * 8;
#pragma unroll
    for (int ks = 0; ks < 3; ++ks) {
        short8 af = {0, 0, 0, 0, 0, 0, 0, 0};
        if (av) af = *(const short8*)(hr + ks * 32);
#pragma unroll
        for (int ct = 0; ct < 3; ++ct)
            acc[ct] = __builtin_amdgcn_mfma_f32_16x16x32_bf16(af, bf[ct][ks], acc[ct], 0, 0, 0);
    }
    int orow = row0 + kh * 4;
    float dn[4];
#pragma unroll
    for (int i = 0; i < 4; ++i)
        dn[i] = (orow + i < N_NODES) ? dinv[orow + i] * 8.f : 0.f;   // SCALE=8
#pragma unroll
    for (int ct = 0; ct < 3; ++ct) {
        int col = ct * 16 + bl;
#pragma unroll
        for (int i = 0; i < 4; ++i) {
            int r = orow + i;
            if (r < N_NODES && (ct < 2 || bl < 8)) {   // cols 0..39 only
                u8 q8 = (u8)enc1(acc[ct][i] * dn[i]);
                hs2P[(size_t)r * 64 + col] = q8;
            }
        }
    }
}

// ---------------- aggregation layer 1: fp8, 12 edges/wave-instr -----------
// 5 lanes/edge: 4 x u32x4 over the 64B hsA8 row + 1 x u32x4 hsB8 row.
// Lane ll holds feats 16ll..16ll+15. Fold 12 groups, epilogue lanes 0..4.
__global__ __launch_bounds__(256) void aggregate1(
        const char* __restrict__ tab, int delta1,
        const int* __restrict__ rowStart, const int* __restrict__ csrSrc,
        const float* __restrict__ dinv, const float* __restrict__ bias,
        u32* __restrict__ out) {
    int wid = threadIdx.x >> 6, lane = threadIdx.x & 63;
    int node = __builtin_amdgcn_readfirstlane(blockIdx.x * 4 + wid);
    if (node >= N_NODES) return;
    int g = lane / 5;                  // pack group 0..11 (12 = inactive)
    int ll = lane - 5 * g;
    bool isB = (ll == 4);
    u32 loff = isB ? (u32)delta1 : (u32)ll * 16;
    int sh = isB ? 4 : 6;              // row stride 16B / 64B
    bool act = lane < 60;
    f32x2 acc[8];
#pragma unroll
    for (int k = 0; k < 8; ++k) { acc[k].x = 0.f; acc[k].y = 0.f; }
    if (lane < 5) {                    // self-loop (group 0 only)
        u32x4 v = *(const u32x4*)(tab + (((u32)node << sh) + loff));
        acc[0] += dec2<0>(v.x); acc[1] += dec2<1>(v.x);
        acc[2] += dec2<0>(v.y); acc[3] += dec2<1>(v.y);
        acc[4] += dec2<0>(v.z); acc[5] += dec2<1>(v.z);
        acc[6] += dec2<0>(v.w); acc[7] += dec2<1>(v.w);
    }
    int j = rowStart[node], end = rowStart[node + 1];
    for (; j + 24 <= end; j += 24) {
        u32 iv[2]; u32x4 vv[2];
#pragma unroll
        for (int q = 0; q < 2; ++q) iv[q] = act ? (u32)csrSrc[j + 12 * q + g] : 0u;
#pragma unroll
        for (int q = 0; q < 2; ++q) {
            u32x4 z = {0u, 0u, 0u, 0u};
            vv[q] = act ? *(const u32x4*)(tab + ((iv[q] << sh) + loff)) : z;
        }
#pragma unroll
        for (int q = 0; q < 2; ++q) {
            acc[0] += dec2<0>(vv[q].x); acc[1] += dec2<1>(vv[q].x);
            acc[2] += dec2<0>(vv[q].y); acc[3] += dec2<1>(vv[q].y);
            acc[4] += dec2<0>(vv[q].z); acc[5] += dec2<1>(vv[q].z);
            acc[6] += dec2<0>(vv[q].w); acc[7] += dec2<1>(vv[q].w);
        }
    }
    for (; j < end; j += 12) {
        bool p = act && (j + g < end);
        u32 ivx = p ? (u32)csrSrc[j + g] : 0u;
        u32x4 z = {0u, 0u, 0u, 0u};
        u32x4 v = p ? *(const u32x4*)(tab + ((ivx << sh) + loff)) : z;
        acc[0] += dec2<0>(v.x); acc[1] += dec2<1>(v.x);
        acc[2] += dec2<0>(v.y); acc[3] += dec2<1>(v.y);
        acc[4] += dec2<0>(v.z); acc[5] += dec2<1>(v.z);
        acc[6] += dec2<0>(v.w); acc[7] += dec2<1>(v.w);
    }
    float tt[16];
#pragma unroll
    for (int k = 0; k < 8; ++k) { tt[2 * k] = acc[k].x; tt[2 * k + 1] = acc[k].y; }
#pragma unroll
    for (int k = 0; k < 16; ++k) {     // fold 12 groups of 5 lanes -> group 0
        tt[k] += __shfl(tt[k], lane + 30);
        tt[k] += __shfl(tt[k], lane + 10) + __shfl(tt[k], lane + 20);
        tt[k] += __shfl(tt[k], lane + 5);
    }
    if (lane < 5) {
        float dns = dinv[node] * 0.125f;   // undo SCALE=8
        u32x4 o0, o1;
#pragma unroll
        for (int k = 0; k < 8; ++k) {
            int f0 = 16 * lane + 2 * k;
            float rlo = (f0 < HID) ? fmaxf(fmaf(dns, tt[2 * k], bias[f0]), 0.f) : 0.f;
            float rhi = (f0 + 1 < HID) ? fmaxf(fmaf(dns, tt[2 * k + 1], bias[f0 + 1]), 0.f) : 0.f;
            u32 wd = ((u32)f2bf(rhi) << 16) | (u32)f2bf(rlo);
            if (k < 4) o0[k] = wd; else o1[k - 4] = wd;
        }
        *(u32x4*)(out + (size_t)node * 48 + 8 * lane) = o0;
        *(u32x4*)(out + (size_t)node * 48 + 8 * lane + 4) = o1;
    }
}

// ---------------- aggregation layer 2: fp8 single table, 12 edges + lsm ---
// 5 lanes/edge x u32x2 over the 64B hs2P row (bytes 0..39 used).
__global__ __launch_bounds__(256) void aggregate2(
        const char* __restrict__ tab,
        const int* __restrict__ rowStart, const int* __restrict__ csrSrc,
        const float* __restrict__ dinv, const float* __restrict__ bias,
        float* __restrict__ out) {
    int wid = threadIdx.x >> 6, lane = threadIdx.x & 63;
    int node = __builtin_amdgcn_readfirstlane(blockIdx.x * 4 + wid);
    if (node >= N_NODES) return;
    int g = lane / 5;                  // pack group 0..11 (12 = inactive)
    int ll = lane - 5 * g;
    u32 loff = (u32)ll * 8;
    bool act = lane < 60;
    f32x2 a0 = {0.f, 0.f}, a1 = {0.f, 0.f}, a2 = {0.f, 0.f}, a3 = {0.f, 0.f};
    if (lane < 5) {                    // self-loop (group 0 only)
        u32x2 v = *(const u32x2*)(tab + (((u32)node << 6) + loff));
        a0 += dec2<0>(v.x); a1 += dec2<1>(v.x);
        a2 += dec2<0>(v.y); a3 += dec2<1>(v.y);
    }
    int j = rowStart[node], end = rowStart[node + 1];
    for (; j + 24 <= end; j += 24) {
        u32 iv[2]; u32x2 vv[2];
#pragma unroll
        for (int q = 0; q < 2; ++q) iv[q] = act ? (u32)csrSrc[j + 12 * q + g] : 0u;
#pragma unroll
        for (int q = 0; q < 2; ++q) {
            u32x2 z = {0u, 0u};
            vv[q] = act ? *(const u32x2*)(tab + ((iv[q] << 6) + loff)) : z;
        }
#pragma unroll
        for (int q = 0; q < 2; ++q) {
            a0 += dec2<0>(vv[q].x); a1 += dec2<1>(vv[q].x);
            a2 += dec2<0>(vv[q].y); a3 += dec2<1>(vv[q].y);
        }
    }
    for (; j < end; j += 12) {
        bool p = act && (j + g < end);
        u32 ivx = p ? (u32)csrSrc[j + g] : 0u;
        u32x2 z = {0u, 0u};
        u32x2 v = p ? *(const u32x2*)(tab + ((ivx << 6) + loff)) : z;
        a0 += dec2<0>(v.x); a1 += dec2<1>(v.x);
        a2 += dec2<0>(v.y); a3 += dec2<1>(v.y);
    }
    float tt[8] = {a0.x, a0.y, a1.x, a1.y, a2.x, a2.y, a3.x, a3.y};
#pragma unroll
    for (int k = 0; k < 8; ++k) {      // fold 12 groups of 5 lanes -> group 0
        tt[k] += __shfl(tt[k], lane + 30);
        tt[k] += __shfl(tt[k], lane + 10) + __shfl(tt[k], lane + 20);
        tt[k] += __shfl(tt[k], lane + 5);
    }
    // softmax over 40 logits: lanes 0..4 hold 8 each (xor-closed over 8 lanes)
    bool act5 = lane < 5;
    float vk[8];
    float m = -3.4e38f;
    if (act5) {
        float dns = dinv[node] * 0.125f;   // undo SCALE=8
#pragma unroll
        for (int k = 0; k < 8; ++k) {
            vk[k] = fmaf(dns, tt[k], bias[8 * ll + k]);
            m = fmaxf(m, vk[k]);
        }
    }
#pragma unroll
    for (int o = 1; o < 8; o <<= 1) m = fmaxf(m, __shfl_xor(m, o));
    float e = 0.f;
    if (act5) {
#pragma unroll
        for (int k = 0; k < 8; ++k) e += expf(vk[k] - m);
    }
#pragma unroll
    for (int o = 1; o < 8; o <<= 1) e += __shfl_xor(e, o);
    float lse = logf(e);
    if (act5) {
        float4 r0 = make_float4(vk[0] - m - lse, vk[1] - m - lse,
                                vk[2] - m - lse, vk[3] - m - lse);
        float4 r1 = make_float4(vk[4] - m - lse, vk[5] - m - lse,
                                vk[6] - m - lse, vk[7] - m - lse);
        *(float4*)(out + (size_t)node * OUT_CH + 8 * ll) = r0;
        *(float4*)(out + (size_t)node * OUT_CH + 8 * ll + 4) = r1;
    }
}

extern "C" void kernel_launch(void* const* d_in, const int* in_sizes, int n_in,
                              void* d_out, int out_size, void* d_ws, size_t ws_size,
                              hipStream_t stream) {
    const float* x  = (const float*)d_in[0];
    const int*   e  = (const int*)d_in[1];
    const float* W1 = (const float*)d_in[2];
    const float* b1 = (const float*)d_in[3];
    const float* W2 = (const float*)d_in[4];
    const float* b2 = (const float*)d_in[5];
    float* out = (float*)d_out;

    // workspace carve (all sizes multiples of 16 B); total ~56 MB
    char* w = (char*)d_ws;
    u8* hsA8 = (u8*)w;                                   // 6.40 MB  (aliases bucketBuf)
    u8* hsB8 = (u8*)(w + 6402048);                       // 1.60 MB  (aliases bucketBuf)
    unsigned* bucketBuf = (unsigned*)w;                  // 15.68 MB, dead after passB
    w += 15680000;
    u16* h1b  = (u16*)w; w += (size_t)100032 * 96 * 2;   // 19.2 MB
    int* csrSrc = (int*)w; w += (size_t)N_EDGES * 4;     // 12.8 MB
    u8* hs2P = (u8*)w; w += (size_t)100032 * 64;         // 6.40 MB
    int* rowStart = (int*)w; w += 400016;
    float* dinv   = (float*)w; w += 400000;
    int* bucketCursor = (int*)w; w += NB * 16 * 4;
    int* bucketStart  = (int*)w; w += 1024;
    u16* w1t = (u16*)w; w += 80 * 128 * 2;
    u16* w2t = (u16*)w; w += 48 * 96 * 2;
    int* flag = (int*)w; w += 16;

    int delta1 = (int)((char*)hsB8 - (char*)hsA8);       // 6,402,048

    probe64<<<1, 256, 0, stream>>>(e, flag);
    init_misc<<<3126, 256, 0, stream>>>(bucketCursor, (u32*)h1b);
    passA<<<(N_EDGES + PA_EDGES - 1) / PA_EDGES, 256, 0, stream>>>(
        e, flag, bucketCursor, bucketBuf);
    scan196<<<1, 256, 0, stream>>>(bucketCursor, bucketStart, rowStart);
    passB<<<NB, 1024, 0, stream>>>(bucketBuf, bucketCursor, bucketStart,
                                   csrSrc, rowStart, dinv);
    prep_w<<<16, 256, 0, stream>>>(W1, W2, w1t, w2t);

    gemm1_mfma<<<(N_NODES + 63) / 64, 256, 0, stream>>>(x, w1t, dinv, hsA8, hsB8);
    aggregate1<<<(N_NODES + 3) / 4, 256, 0, stream>>>(
        (const char*)hsA8, delta1, rowStart, csrSrc, dinv, b1, (u32*)h1b);
    gemm2_mfma<<<(N_NODES + 63) / 64, 256, 0, stream>>>(h1b, w2t, dinv, hs2P);
    aggregate2<<<(N_NODES + 3) / 4, 256, 0, stream>>>(
        (const char*)hs2P, rowStart, csrSrc, dinv, b2, out);
}